// Round 15
// baseline (320.910 us; speedup 1.0000x reference)
//
#include <hip/hip_runtime.h>
#include <hip/hip_bf16.h>
#include <math.h>

#define NN 50000
#define NE 800000
#define HD 128
#define FD 16
#define NPATH 16
#define PL 8
#define NM 6
#define NS 320
#define NSB 782   // ceil(NN/64)
#define AK 320    // K for iters 2-3 GEMM (hsum128 | h128 | ef16 | deg | 1 | pad)
#define A2S 192   // shorts per A2 row (hsum128 | statics64)
#define A2U 96    // uints per A2 row
#define HU 64     // uints per H row
#define AK1 64    // K for iter-1 GEMM (nf16 | nfsum16 | ef16 | deg | 1 | pad)
#define EPB 2048  // edges per histogram/scatter block
#define NBLK 391  // ceil(NE/EPB)
#define NBKT 196  // buckets = dst>>8
#define MBT 391   // ceil(NN/128) m-tiles
#define NEGV -1000000000.0f

typedef unsigned int uint;
typedef unsigned short ushort;
typedef short bf16x8 __attribute__((ext_vector_type(8)));
typedef float f32x4 __attribute__((ext_vector_type(4)));

// fast transcendentals: v_exp_f32 + v_rcp_f32
__device__ __forceinline__ float frcp(float x){ return __builtin_amdgcn_rcpf(x); }
__device__ __forceinline__ float fsigm(float x){ return frcp(1.0f + __expf(-x)); }
__device__ __forceinline__ float ftanh(float x){ return 1.0f - 2.0f*frcp(__expf(2.0f*x) + 1.0f); }

// native bf16 convert
__device__ __forceinline__ ushort f2b(float f){
    union { __hip_bfloat16 h; ushort u; } v;
    v.h = __float2bfloat16(f);
    return v.u;
}
__device__ __forceinline__ float b2f(ushort s){
    union{uint u; float f;} v; v.u = ((uint)s)<<16; return v.f;
}
__device__ __forceinline__ float blo(uint v){ return b2f((ushort)(v&0xFFFF)); }
__device__ __forceinline__ float bhi(uint v){ return b2f((ushort)(v>>16)); }
__device__ __forceinline__ uint pack2(float a, float b){ return (uint)f2b(a) | (((uint)f2b(b))<<16); }

// async global->LDS 16B per lane; LDS dest wave-uniform, global src per-lane
__device__ __forceinline__ void gload16(const void* g, void* l){
    __builtin_amdgcn_global_load_lds(
        (const __attribute__((address_space(1))) unsigned int*)g,
        (__attribute__((address_space(3))) unsigned int*)l,
        16, 0, 0);
}

// ---- counting sort phase 1: per-block bucket histogram ----
__global__ void k_hist(const int* __restrict__ ei, int* __restrict__ C){
    __shared__ int h[NBKT];
    int tid = threadIdx.x, blk = blockIdx.x;
    if (tid < NBKT) h[tid] = 0;
    __syncthreads();
    int e0 = blk*EPB;
    for (int i=tid; i<EPB; i+=256){
        int e = e0+i;
        if (e < NE) atomicAdd(&h[ei[NE+e]>>8], 1);
    }
    __syncthreads();
    if (tid < NBKT) C[blk*NBKT + tid] = h[tid];
}

// ---- phase 2a: per-bucket exclusive prefix over blocks + bucket totals ----
__global__ void k_cscanA(int* __restrict__ C, int* __restrict__ bkttot){
    int b = blockIdx.x*4 + (threadIdx.x>>6);
    int lane = threadIdx.x & 63;
    if (b >= NBKT) return;
    int carry = 0;
    for (int c=0; c<7; ++c){
        int i = c*64 + lane;
        int v = (i<NBLK)? C[i*NBKT + b] : 0;
        int x = v;
        #pragma unroll
        for (int d=1; d<64; d<<=1){ int y = __shfl_up(x,d); if (lane>=d) x += y; }
        if (i<NBLK) C[i*NBKT + b] = carry + (x - v);
        carry += __shfl(x, 63);
    }
    if (lane==0) bkttot[b] = carry;
}

// ---- phase 2b: scan bucket totals -> bucket bases; offs[NN]=NE ----
__global__ void k_bscan(const int* __restrict__ bkttot, int* __restrict__ bktbase,
                        int* __restrict__ offs){
    int tid = threadIdx.x, lane = tid&63, w = tid>>6;
    int v = (tid<NBKT)? bkttot[tid] : 0;
    int x = v;
    #pragma unroll
    for (int d=1; d<64; d<<=1){ int y = __shfl_up(x,d); if (lane>=d) x += y; }
    __shared__ int wsum[4];
    if (lane==63) wsum[w] = x;
    __syncthreads();
    int base = 0;
    #pragma unroll
    for (int j=0;j<4;j++) if (j<w) base += wsum[j];
    int excl = base + x - v;
    if (tid < NBKT) bktbase[tid] = excl;
    if (tid == NBKT){ bktbase[NBKT] = excl; offs[NN] = excl; }
}

// ---- phase 3: scatter edges into bucket-ordered array ----
__global__ void k_scatA(const int* __restrict__ ei, const int* __restrict__ C,
                        const int* __restrict__ bktbase, int2* __restrict__ bkt2){
    __shared__ int cur[NBKT];
    __shared__ int cbase[NBKT];
    int tid = threadIdx.x, blk = blockIdx.x;
    if (tid < NBKT){ cur[tid] = 0; cbase[tid] = bktbase[tid] + C[blk*NBKT + tid]; }
    __syncthreads();
    int e0 = blk*EPB;
    for (int i=tid; i<EPB; i+=256){
        int e = e0+i;
        if (e >= NE) break;
        int dst = ei[NE+e];
        int bkt = dst>>8;
        int r = atomicAdd(&cur[bkt], 1);
        bkt2[cbase[bkt] + r] = make_int2(dst, e);
    }
}

// ---- phase 4: per-bucket per-dst counts + scan -> offs; exact placement ----
__global__ void k_scatB(const int* __restrict__ ei, const int2* __restrict__ bkt2,
                        const int* __restrict__ bktbase,
                        int* __restrict__ offs, int2* __restrict__ csr2){
    __shared__ int cnt[256];
    __shared__ int cur[256];
    __shared__ int wsum[4];
    int b = blockIdx.x, tid = threadIdx.x, lane = tid&63, w = tid>>6;
    int d0 = b<<8;
    cnt[tid] = 0;
    __syncthreads();
    int lo = bktbase[b], hi = bktbase[b+1];
    for (int i=lo+tid; i<hi; i+=256) atomicAdd(&cnt[bkt2[i].x & 255], 1);
    __syncthreads();
    int v = cnt[tid], x = v;
    #pragma unroll
    for (int d=1; d<64; d<<=1){ int y = __shfl_up(x,d); if (lane>=d) x += y; }
    if (lane==63) wsum[w] = x;
    __syncthreads();
    int base = 0;
    #pragma unroll
    for (int j=0;j<4;j++) if (j<w) base += wsum[j];
    int o = lo + base + x - v;
    if (d0+tid < NN) offs[d0+tid] = o;
    cur[tid] = o;
    __syncthreads();
    for (int i=lo+tid; i<hi; i+=256){
        int2 p = bkt2[i];
        int pos = atomicAdd(&cur[p.x & 255], 1);
        csr2[pos] = make_int2(ei[p.y], p.y);
    }
}

// ---- per-node 16-wide sums of edge_feat (by eid) and node_feat (by src) ----
__global__ void k_gat16(const int2* __restrict__ csr2,
                        const float* __restrict__ edge_feat, const float* __restrict__ nf,
                        const int* __restrict__ offs,
                        float* __restrict__ ef_sum, float* __restrict__ nf_sum){
    int node = blockIdx.x*4 + (threadIdx.x>>6);
    int lane = threadIdx.x & 63;
    int k = lane & 15, sub = lane >> 4;
    int b = offs[node], e2 = offs[node+1];
    float ae = 0.f, an = 0.f;
    int i = b + sub;
    for (; i + 4 < e2; i += 8){
        int2 p0 = csr2[i], p1 = csr2[i+4];
        float f0 = edge_feat[(size_t)p0.y*FD + k];
        float g0 = nf[(size_t)p0.x*FD + k];
        float f1 = edge_feat[(size_t)p1.y*FD + k];
        float g1 = nf[(size_t)p1.x*FD + k];
        ae += f0 + f1; an += g0 + g1;
    }
    if (i < e2){
        int2 p0 = csr2[i];
        ae += edge_feat[(size_t)p0.y*FD + k];
        an += nf[(size_t)p0.x*FD + k];
    }
    ae += __shfl_xor(ae, 16); ae += __shfl_xor(ae, 32);
    an += __shfl_xor(an, 16); an += __shfl_xor(an, 32);
    if (sub == 0){ ef_sum[node*FD + k] = ae; nf_sum[node*FD + k] = an; }
}

// ---- Wf = W_ep@W_e ; bfv = b_ep@W_e + b_msg ----
__global__ void k_folds(const float* __restrict__ W_ep, const float* __restrict__ b_ep,
                        const float* __restrict__ W_msg, const float* __restrict__ b_msg,
                        float* __restrict__ Wf, float* __restrict__ bfv){
    int o = blockIdx.x*256 + threadIdx.x;
    if (o < FD*HD){
        int k=o>>7, c=o&127;
        float acc=0.f;
        for (int m=0;m<HD;m++) acc += W_ep[k*HD+m]*W_msg[(HD+m)*HD+c];
        Wf[o]=acc;
    } else if (o < FD*HD+HD){
        int c=o-FD*HD;
        float acc=b_msg[c];
        for (int m=0;m<HD;m++) acc += b_ep[m]*W_msg[(HD+m)*HD+c];
        bfv[c]=acc;
    }
}

// ---- build folded mega-weight W2T[512][320], col-INTERLEAVED gates: col = 4*j + g ----
__global__ void k_wprep2(const float* __restrict__ W_ih, const float* __restrict__ W_hh,
                         const float* __restrict__ W_msg, const float* __restrict__ Wf,
                         const float* __restrict__ bfv,
                         const float* __restrict__ b_ih, const float* __restrict__ b_hh,
                         ushort* __restrict__ W2T, float* __restrict__ Wt32){
    int c = blockIdx.x;       // 0..511
    int k = threadIdx.x;      // 0..319
    int j = c>>2, g = c&3;
    float v = 0.f;
    if (k < 128){
        float acc = 0.f;
        if (g < 3){   // hsum path: (W_h @ W_ih_g^T)
            const float* wm = W_msg + (size_t)k*HD;
            const float* wi = W_ih + (size_t)(g*HD+j)*HD;
            for (int m=0;m<HD;m++) acc += wm[m]*wi[m];
        }
        Wt32[(size_t)c*HD + k] = acc;
        v = acc;
    } else if (k < 256){      // h path: W_hh gates (none for gi_n)
        int kk = k-128;
        if (g==0)      v = W_hh[(size_t)j*HD+kk];
        else if (g==1) v = W_hh[(size_t)(HD+j)*HD+kk];
        else if (g==3) v = W_hh[(size_t)(2*HD+j)*HD+kk];
    } else if (k < 272){      // ef_sum path
        if (g < 3){
            const float* wf = Wf + (size_t)(k-256)*HD;
            const float* wi = W_ih + (size_t)(g*HD+j)*HD;
            float acc=0.f;
            for (int m=0;m<HD;m++) acc += wf[m]*wi[m];
            v = acc;
        }
    } else if (k == 272){     // deg path
        if (g < 3){
            const float* wi = W_ih + (size_t)(g*HD+j)*HD;
            float acc=0.f;
            for (int m=0;m<HD;m++) acc += bfv[m]*wi[m];
            v = acc;
        }
    } else if (k == 273){     // constant-1: biases
        v = (g==0)? b_ih[j]+b_hh[j] : (g==1)? b_ih[HD+j]+b_hh[HD+j]
          : (g==2)? b_ih[2*HD+j] : b_hh[2*HD+j];
    }
    W2T[(size_t)c*AK + k] = f2b(v);
}

// ---- iter-1 weight W1T[512][64] ----
__global__ void k_wprep1(const float* __restrict__ W_np, const float* __restrict__ b_np,
                         const float* __restrict__ W_hh, const float* __restrict__ Wt32,
                         const ushort* __restrict__ W2T, ushort* __restrict__ W1T){
    int c = blockIdx.x;       // 0..511
    int k = threadIdx.x;      // 0..63
    int j = c>>2, g = c&3;
    float v = 0.f;
    if (k < 16){              // nf path: W_np @ W_hh_g^T  (g2 has no h-term)
        if (g != 2){
            int gp = (g==3)? 2 : g;
            const float* wh = W_hh + (size_t)(gp*HD + j)*HD;
            const float* wn = W_np + (size_t)k*HD;
            float acc=0.f;
            for (int m=0;m<HD;m++) acc += wn[m]*wh[m];
            v = acc;
        }
    } else if (k < 32){       // nf_sum path
        const float* wt = Wt32 + (size_t)c*HD;
        const float* wn = W_np + (size_t)(k-16)*HD;
        float acc=0.f;
        for (int m=0;m<HD;m++) acc += wn[m]*wt[m];
        v = acc;
    } else if (k < 48){       // ef_sum path: copy from W2T
        v = b2f(W2T[(size_t)c*AK + 256 + (k-32)]);
    } else if (k == 48){      // deg
        float acc = b2f(W2T[(size_t)c*AK + 272]);
        const float* wt = Wt32 + (size_t)c*HD;
        for (int m=0;m<HD;m++) acc += b_np[m]*wt[m];
        v = acc;
    } else if (k == 49){      // const-1
        float acc = b2f(W2T[(size_t)c*AK + 273]);
        if (g != 2){
            int gp = (g==3)? 2 : g;
            const float* wh = W_hh + (size_t)(gp*HD + j)*HD;
            for (int m=0;m<HD;m++) acc += b_np[m]*wh[m];
        }
        v = acc;
    }
    W1T[(size_t)c*AK1 + k] = f2b(v);
}

// ---- light prep: A1p[NN][64] = [nf|nfsum|ef|deg|1|0]; statics into A2 ----
__global__ void k_prep2(const float* __restrict__ nf, const float* __restrict__ nf_sum,
                        const float* __restrict__ ef_sum, const int* __restrict__ offs,
                        ushort* __restrict__ A1p, ushort* __restrict__ A2){
    int idx = blockIdx.x*256 + threadIdx.x;   // NN*32
    int n = idx>>5, c2 = idx&31;
    int k = c2*2, k1 = k+1;
    float d = (float)(offs[n+1] - offs[n]);
    float v0 = (k<16)? nf[n*FD+k] : (k<32)? nf_sum[n*FD+k-16] : (k<48)? ef_sum[n*FD+k-32]
             : (k==48)? d : 0.f;
    float v1 = (k1<16)? nf[n*FD+k1] : (k1<32)? nf_sum[n*FD+k1-16] : (k1<48)? ef_sum[n*FD+k1-32]
             : (k1==49)? 1.f : 0.f;
    ((uint*)A1p)[(size_t)n*32 + c2] = pack2(v0,v1);
    int s = k;   // static col 0..63 maps to W2T k=256+s
    float s0 = (s<16)? ef_sum[n*FD + s] : (s==16)? d : 0.f;
    float s1 = (s+1<16)? ef_sum[n*FD + s+1] : (s+1==17)? 1.f : 0.f;
    ((uint*)A2)[(size_t)n*A2U + 64 + c2] = pack2(s0,s1);
}

// ---- fused GEMM + GRU, BN=256 (both gate-pairs), 512 threads / 8 waves ----
// grid 784: xcd=bid&7, npair=(bid>>3)&1, mt = xcd + 8*(bid>>4)
// K sources (iters 2-3): kk0,1 = A2.hsum; kk2,3 = Hp; kk4 = A2.statics. Race-free ping-pong.
template<bool IT1>
__global__ __launch_bounds__(512, 4) void k_fused(const ushort* __restrict__ Asrc,
                                                  const ushort* __restrict__ Bt,
                                                  const ushort* __restrict__ Hp,
                                                  const float* __restrict__ nf,
                                                  const float* __restrict__ W_np,
                                                  const float* __restrict__ b_np,
                                                  ushort* __restrict__ Hn){
    __shared__ __align__(16) short LDS[128*64 + 256*64];   // 48KB: As 16K | Bs 32K
    short* As = LDS;
    short* Bs = LDS + 128*64;
    const int bid = blockIdx.x;
    const int xcd = bid & 7;
    const int t = bid >> 3;
    const int npair = t & 1;
    const int mt = xcd + ((t >> 1) << 3);
    if (mt >= MBT) return;
    const int tid = threadIdx.x;
    const int lane = tid & 63, w = tid>>6;         // 8 waves
    const int wm = w>>2, wn = w&3;
    const int n0 = npair*256, m0 = mt*128;
    const int rl  = lane>>3;                       // row-in-chunk 0..7
    const int sg  = (lane&7) ^ rl;                 // pre-swizzled global slot
    f32x4 acc[4][4] = {};
    const int nsteps = IT1 ? 1 : 5;
    for (int kk=0; kk<nsteps; ++kk){
        __syncthreads();
        #pragma unroll
        for (int i=0;i<6;i++){
            int idx = w*6 + i;                     // 0..47
            if (idx < 16){                         // A chunks
                int rowl = (idx<<3) + rl;
                int ar = m0 + rowl; if (ar >= NN) ar = NN-1;
                const ushort* ap;
                if constexpr (IT1) ap = Asrc + (size_t)ar*AK1 + sg*8;
                else {
                    if (kk < 2)      ap = Asrc + (size_t)ar*A2S + kk*64 + sg*8;
                    else if (kk < 4) ap = Hp   + (size_t)ar*HD  + (kk-2)*64 + sg*8;
                    else             ap = Asrc + (size_t)ar*A2S + 128 + sg*8;
                }
                gload16(ap, As + idx*512);
            } else {                               // B chunks
                int bi = idx - 16;                 // 0..31
                int rowl = (bi<<3) + rl;
                const int AKB = IT1 ? AK1 : AK;
                gload16(Bt + (size_t)(n0+rowl)*AKB + kk*64 + sg*8, Bs + bi*512);
            }
        }
        __syncthreads();
        #pragma unroll
        for (int ksel=0; ksel<2; ++ksel){
            bf16x8 af[4], bfr[4];
            #pragma unroll
            for (int t2=0;t2<4;t2++){
                int arow = wm*64 + t2*16 + (lane&15);
                int aslot = (ksel*4 + (lane>>4)) ^ (arow&7);
                af[t2] = *(const bf16x8*)&As[arow*64 + aslot*8];
                int brow = wn*64 + t2*16 + (lane&15);
                int bslot = (ksel*4 + (lane>>4)) ^ (brow&7);
                bfr[t2] = *(const bf16x8*)&Bs[brow*64 + bslot*8];
            }
            #pragma unroll
            for (int mi=0;mi<4;mi++)
                #pragma unroll
                for (int ni=0;ni<4;ni++)
                    acc[mi][ni] = __builtin_amdgcn_mfma_f32_16x16x32_bf16(af[mi], bfr[ni], acc[mi][ni], 0,0,0);
        }
    }
    // epilogue in two 128-col halves (reuses first 32KB of LDS for the gate tile)
    #pragma unroll
    for (int h=0; h<2; ++h){
        __syncthreads();
        if ((wn>>1) == h){
            int cw = wn & 1;
            #pragma unroll
            for (int mi=0;mi<4;mi++){
                #pragma unroll
                for (int ni=0;ni<4;ni++){
                    #pragma unroll
                    for (int r=0;r<4;r++){
                        int row = wm*64 + mi*16 + (lane>>4)*4 + r;
                        int col = cw*64 + ni*16 + (lane&15);       // 0..127 within half
                        int pc = (col&3) | (((col>>2) ^ (row&7))<<2);
                        LDS[row*128 + pc] = (short)f2b(acc[mi][ni][r]);
                    }
                }
            }
        }
        __syncthreads();
        // GRU: all 512 threads; jp = tid&15 (j-pair), rg = tid>>4 (4 rows each)
        {
            int jp = tid&15, rg = tid>>4;
            int jg = npair*128 + h*64 + jp*2;       // global hidden j (first of pair)
            int hoff = npair*32 + h*16 + jp;        // uint offset within H row
            #pragma unroll
            for (int rr=0; rr<4; ++rr){
                int row = rg*4 + rr;
                int n = m0 + row;
                if (n >= NN) continue;
                uint2 g0 = *(const uint2*)&LDS[row*128 + (((jp*2)   ^ (row&7))<<2)];
                uint2 g1 = *(const uint2*)&LDS[row*128 + (((jp*2+1) ^ (row&7))<<2)];
                float ha, hb;
                if constexpr (IT1){
                    const float* x = nf + (size_t)n*FD;
                    float a = b_np[jg], b = b_np[jg+1];
                    #pragma unroll
                    for (int k=0;k<FD;k++){
                        float xv = x[k];
                        a += xv*W_np[k*HD + jg];
                        b += xv*W_np[k*HD + jg + 1];
                    }
                    ha = a; hb = b;
                } else {
                    uint vh = ((const uint*)Hp)[(size_t)n*HU + hoff];
                    ha = blo(vh); hb = bhi(vh);
                }
                float r0 = fsigm(blo(g0.x)), z0 = fsigm(bhi(g0.x));
                float nn0 = ftanh(blo(g0.y) + r0*bhi(g0.y));
                float r1 = fsigm(blo(g1.x)), z1 = fsigm(bhi(g1.x));
                float nn1 = ftanh(blo(g1.y) + r1*bhi(g1.y));
                float h0 = (1.f-z0)*nn0 + z0*ha;
                float h1 = (1.f-z1)*nn1 + z1*hb;
                ((uint*)Hn)[(size_t)n*HU + hoff] = pack2(h0,h1);
            }
        }
    }
}

// ---- hsum[n] = sum over in-edges of H[src] -> A2.hsum ----
__global__ void k_gather(ushort* __restrict__ A2, const int* __restrict__ offs,
                         const int2* __restrict__ csr2, const ushort* __restrict__ H){
    int node = blockIdx.x*4 + (threadIdx.x>>6);
    int c2 = threadIdx.x & 63;
    int b = offs[node], e2 = offs[node+1];
    float a0 = 0.f, a1 = 0.f;
    const uint* hp = (const uint*)H;
    int i = b;
    for (; i + 8 <= e2; i += 8){
        int s0=csr2[i].x,  s1=csr2[i+1].x, s2=csr2[i+2].x, s3=csr2[i+3].x;
        int s4=csr2[i+4].x,s5=csr2[i+5].x, s6=csr2[i+6].x, s7=csr2[i+7].x;
        uint v0=hp[(size_t)s0*HU+c2], v1=hp[(size_t)s1*HU+c2],
             v2=hp[(size_t)s2*HU+c2], v3=hp[(size_t)s3*HU+c2],
             v4=hp[(size_t)s4*HU+c2], v5=hp[(size_t)s5*HU+c2],
             v6=hp[(size_t)s6*HU+c2], v7=hp[(size_t)s7*HU+c2];
        a0 += blo(v0)+blo(v1)+blo(v2)+blo(v3)+blo(v4)+blo(v5)+blo(v6)+blo(v7);
        a1 += bhi(v0)+bhi(v1)+bhi(v2)+bhi(v3)+bhi(v4)+bhi(v5)+bhi(v6)+bhi(v7);
    }
    if (i + 4 <= e2){
        int s0=csr2[i].x,s1=csr2[i+1].x,s2=csr2[i+2].x,s3=csr2[i+3].x;
        uint v0=hp[(size_t)s0*HU+c2], v1=hp[(size_t)s1*HU+c2],
             v2=hp[(size_t)s2*HU+c2], v3=hp[(size_t)s3*HU+c2];
        a0 += blo(v0)+blo(v1)+blo(v2)+blo(v3);
        a1 += bhi(v0)+bhi(v1)+bhi(v2)+bhi(v3);
        i += 4;
    }
    for (; i < e2; ++i){
        uint v = hp[(size_t)csr2[i].x*HU+c2];
        a0 += blo(v); a1 += bhi(v);
    }
    ((uint*)A2)[(size_t)node*A2U + c2] = pack2(a0,a1);
}

// ---- two-stage column sum of final H ----
__global__ void k_sum1(const ushort* __restrict__ H, float* __restrict__ partial){
    int bid = blockIdx.x, tid = threadIdx.x;
    int lane = tid&63, w2 = tid>>6;
    int nb = bid*64;
    float a0=0.f, a1=0.f;
    const uint* hp = (const uint*)H;
    #pragma unroll
    for (int r=w2; r<64; r+=4){
        int n = nb + r;
        if (n < NN){
            uint v = hp[(size_t)n*HU + lane];
            a0 += blo(v); a1 += bhi(v);
        }
    }
    __shared__ float s0[4][64], s1[4][64];
    s0[w2][lane]=a0; s1[w2][lane]=a1;
    __syncthreads();
    if (w2==0){
        a0 = s0[0][lane]+s0[1][lane]+s0[2][lane]+s0[3][lane];
        a1 = s1[0][lane]+s1[1][lane]+s1[2][lane]+s1[3][lane];
        ((float2*)partial)[(size_t)bid*64 + lane] = make_float2(a0,a1);
    }
}
__global__ void k_sum2(const float* __restrict__ partial, float* __restrict__ gsum){
    int c = blockIdx.x;          // 0..127
    int tid = threadIdx.x;       // 256
    int lane = tid&63, w = tid>>6;
    float a = 0.f;
    for (int b=tid; b<NSB; b+=256) a += partial[(size_t)b*128 + c];
    #pragma unroll
    for (int d=1; d<64; d<<=1) a += __shfl_xor(a, d);
    __shared__ float sh[4];
    if (lane==0) sh[w]=a;
    __syncthreads();
    if (tid==0) gsum[c] = sh[0]+sh[1]+sh[2]+sh[3];
}

// ---- tiny agents + value head, LDS-staged z + wave-parallel reductions ----
__global__ void k_small(const float* __restrict__ ef, const int* __restrict__ paths,
                        const int* __restrict__ pmask, const float* __restrict__ pfeat,
                        const int* __restrict__ mmask, const int* __restrict__ smask,
                        const float* __restrict__ pspec,
                        const float* __restrict__ W_ep, const float* __restrict__ b_ep,
                        const float* __restrict__ W_path, const float* __restrict__ b_path,
                        const float* __restrict__ W_mod, const float* __restrict__ b_mod,
                        const float* __restrict__ c1w, const float* __restrict__ c1b,
                        const float* __restrict__ c2w, const float* __restrict__ c2b,
                        const float* __restrict__ W_val, const float* __restrict__ b_val,
                        const float* __restrict__ gsum, float* __restrict__ out){
    __shared__ float Wep_s[FD][HD];   // 8KB
    __shared__ float esum[NPATH][FD]; // 1KB
    __shared__ float z[NPATH][HD];
    __shared__ float lf[NS];
    __shared__ float spec[NS];
    __shared__ float red[8];
    __shared__ float scal[3];
    __shared__ int   sel[3];
    __shared__ float maxsh;
    int tid = threadIdx.x, lane = tid&63, w = tid>>6;

    for (int i=tid; i<FD*HD; i+=512) Wep_s[i>>7][i&127] = W_ep[i];
    if (tid < NPATH*FD){
        int p = tid>>4, k = tid&15;
        float a = 0.f;
        #pragma unroll
        for (int l=0;l<PL;l++){
            int eid = paths[p*PL + l];
            a += ef[(size_t)eid*FD + k];
        }
        esum[p][k] = a*0.125f;
    }
    __syncthreads();
    #pragma unroll
    for (int i=tid; i<NPATH*HD; i+=512){
        int p = i>>7, c = i&127;
        float a = b_ep[c];
        #pragma unroll
        for (int k=0;k<FD;k++) a += esum[p][k]*Wep_s[k][c];
        z[p][c] = a;
    }
    __syncthreads();
    { // logits_p
        int p = tid>>5, sub = tid&31;
        float part = 0.f;
        #pragma unroll
        for (int c=sub;c<HD;c+=32) part += z[p][c]*W_path[c];
        #pragma unroll
        for (int d=16; d>=1; d>>=1) part += __shfl_xor(part, d);
        if (sub==0) lf[p] = (pmask[p]==0)? NEGV : part + b_path[0];
    }
    __syncthreads();
    if (w==0){
        float v = (lane<NPATH)? lf[lane] : -3.0e38f;
        float m = v;
        #pragma unroll
        for (int d=1; d<64; d<<=1) m = fmaxf(m, __shfl_xor(m, d));
        float e = (lane<NPATH)? __expf(v-m) : 0.f;
        #pragma unroll
        for (int d=1; d<64; d<<=1) e += __shfl_xor(e, d);
        int idx = (lane<NPATH && v==m)? lane : (1<<30);
        #pragma unroll
        for (int d=1; d<64; d<<=1) idx = min(idx, __shfl_xor(idx, d));
        if (lane==0){ sel[0]=idx; scal[0] = -logf(e); }
    }
    __syncthreads();
    int pstar = sel[0];
    if (w < NM){
        float part = 0.f;
        #pragma unroll
        for (int c=lane;c<HD;c+=64) part += z[pstar][c]*W_mod[c*NM + w];
        if (lane<3) part += pfeat[pstar*3+lane]*W_mod[(HD+lane)*NM + w];
        #pragma unroll
        for (int d=1; d<64; d<<=1) part += __shfl_xor(part, d);
        if (lane==0) red[w] = (mmask[pstar*NM + w]==0)? NEGV : part + b_mod[w];
    } else if (w == 7){
        float part = gsum[lane]*W_val[lane] + gsum[lane+64]*W_val[lane+64];
        #pragma unroll
        for (int d=1; d<64; d<<=1) part += __shfl_xor(part, d);
        if (lane==0) scal[2] = part/(float)NN + b_val[0];
    }
    __syncthreads();
    if (w==0){
        float v = (lane<NM)? red[lane] : -3.0e38f;
        float m = v;
        #pragma unroll
        for (int d=1; d<64; d<<=1) m = fmaxf(m, __shfl_xor(m, d));
        float e = (lane<NM)? __expf(v-m) : 0.f;
        #pragma unroll
        for (int d=1; d<64; d<<=1) e += __shfl_xor(e, d);
        int idx = (lane<NM && v==m)? lane : (1<<30);
        #pragma unroll
        for (int d=1; d<64; d<<=1) idx = min(idx, __shfl_xor(idx, d));
        if (lane==0){ sel[1]=idx; scal[1] = -logf(e); }
    }
    __syncthreads();
    int mstar = sel[1];
    if (tid < NS) spec[tid] = pspec[pstar*NS + tid];
    __syncthreads();
    float v = -3.0e38f;
    if (tid < NS){
        float acc = c2b[0];
        #pragma unroll
        for (int ch=0; ch<8; ch++){
            float a = c1b[ch];
            #pragma unroll
            for (int k=0;k<5;k++){
                int ss = tid + k - 2;
                if (ss>=0 && ss<NS) a += spec[ss]*c1w[ch*5+k];
            }
            a = fmaxf(a, 0.f);
            acc += a*c2w[ch];
        }
        v = (smask[pstar*NM*NS + mstar*NS + tid]==0) ? NEGV : acc;
    }
    float m = v;
    #pragma unroll
    for (int d=1; d<64; d<<=1) m = fmaxf(m, __shfl_xor(m, d));
    if (lane==0) red[w] = m;
    __syncthreads();
    if (tid==0){
        float mm = red[0];
        #pragma unroll
        for (int i=1;i<8;i++) mm = fmaxf(mm, red[i]);
        maxsh = mm; sel[2] = 1<<30;
    }
    __syncthreads();
    float M2 = maxsh;
    if (tid<NS && v==M2) atomicMin(&sel[2], tid);
    float e = (tid<NS)? __expf(v-M2) : 0.f;
    #pragma unroll
    for (int d=1; d<64; d<<=1) e += __shfl_xor(e, d);
    if (lane==0) red[w] = e;
    __syncthreads();
    if (tid==0){
        float se = 0.f;
        #pragma unroll
        for (int i=0;i<8;i++) se += red[i];
        out[0] = (float)pstar;
        out[1] = (float)sel[2];
        out[2] = (float)mstar;
        out[3] = scal[0] + scal[1] - logf(se);
        out[4] = scal[2];
    }
}

extern "C" void kernel_launch(void* const* d_in, const int* in_sizes, int n_in,
                              void* d_out, int out_size, void* d_ws, size_t ws_size,
                              hipStream_t stream) {
    (void)in_sizes; (void)n_in; (void)out_size; (void)ws_size;
    const float* node_feat     = (const float*)d_in[0];
    const float* edge_feat     = (const float*)d_in[1];
    const int*   edge_index    = (const int*)d_in[2];
    const int*   paths         = (const int*)d_in[3];
    const int*   path_mask     = (const int*)d_in[4];
    const float* path_features = (const float*)d_in[5];
    const int*   mod_masks     = (const int*)d_in[6];
    const int*   spec_masks    = (const int*)d_in[7];
    const float* path_spectrum = (const float*)d_in[8];
    const float* W_np  = (const float*)d_in[9];
    const float* b_np  = (const float*)d_in[10];
    const float* W_ep  = (const float*)d_in[11];
    const float* b_ep  = (const float*)d_in[12];
    const float* W_msg = (const float*)d_in[13];
    const float* b_msg = (const float*)d_in[14];
    const float* W_ih  = (const float*)d_in[15];
    const float* b_ih  = (const float*)d_in[16];
    const float* W_hh  = (const float*)d_in[17];
    const float* b_hh  = (const float*)d_in[18];
    const float* W_path = (const float*)d_in[19];
    const float* b_path = (const float*)d_in[20];
    const float* W_mod  = (const float*)d_in[21];
    const float* b_mod  = (const float*)d_in[22];
    const float* c1w = (const float*)d_in[23];
    const float* c1b = (const float*)d_in[24];
    const float* c2w = (const float*)d_in[25];
    const float* c2b = (const float*)d_in[26];
    const float* W_val = (const float*)d_in[27];
    const float* b_val = (const float*)d_in[28];

    char* ws = (char*)d_ws;
    size_t off = 0;
    auto alloc = [&](size_t bytes)->char*{
        char* p = ws + off;
        off += (bytes + 255) & ~(size_t)255;
        return p;
    };
    int*    offs    = (int*)alloc((size_t)(NN+1)*4);
    int*    Cmat    = (int*)alloc((size_t)NBLK*NBKT*4);
    int*    bkttot  = (int*)alloc((size_t)NBKT*4);
    int*    bktbase = (int*)alloc((size_t)(NBKT+1)*4);
    int2*   bkt2    = (int2*)alloc((size_t)NE*8);
    int2*   csr2    = (int2*)alloc((size_t)NE*8);
    float*  ef_sum  = (float*)alloc((size_t)NN*FD*4);
    float*  nf_sum  = (float*)alloc((size_t)NN*FD*4);
    float*  Wf      = (float*)alloc((size_t)FD*HD*4);
    float*  bfv     = (float*)alloc((size_t)HD*4);
    ushort* W2T     = (ushort*)alloc((size_t)512*AK*2);
    float*  Wt32    = (float*)alloc((size_t)512*HD*4);
    ushort* W1T     = (ushort*)alloc((size_t)512*AK1*2);
    ushort* A2      = (ushort*)alloc((size_t)NN*A2S*2);
    ushort* A1p     = (ushort*)alloc((size_t)NN*AK1*2);
    ushort* H0      = (ushort*)alloc((size_t)NN*HD*2);
    ushort* H1      = (ushort*)alloc((size_t)NN*HD*2);
    float*  partial = (float*)alloc((size_t)NSB*HD*4);
    float*  gsum    = (float*)alloc((size_t)HD*4);

    k_hist<<<NBLK, 256, 0, stream>>>(edge_index, Cmat);
    k_cscanA<<<(NBKT+3)/4, 256, 0, stream>>>(Cmat, bkttot);
    k_bscan<<<1, 256, 0, stream>>>(bkttot, bktbase, offs);
    k_scatA<<<NBLK, 256, 0, stream>>>(edge_index, Cmat, bktbase, bkt2);
    k_scatB<<<NBKT, 256, 0, stream>>>(edge_index, bkt2, bktbase, offs, csr2);
    k_gat16<<<NN/4, 256, 0, stream>>>(csr2, edge_feat, node_feat, offs, ef_sum, nf_sum);
    k_folds<<<9, 256, 0, stream>>>(W_ep, b_ep, W_msg, b_msg, Wf, bfv);
    k_wprep2<<<512, AK, 0, stream>>>(W_ih, W_hh, W_msg, Wf, bfv, b_ih, b_hh, W2T, Wt32);
    k_wprep1<<<512, AK1, 0, stream>>>(W_np, b_np, W_hh, Wt32, W2T, W1T);
    k_prep2<<<NN*32/256, 256, 0, stream>>>(node_feat, nf_sum, ef_sum, offs, A1p, A2);

    const int GRID = 8*2*49;   // 784 (xcd, npair, m-chunk); 4 slots idle
    // iter 1: A1p (K=64) -> fused GRU -> H0  (h0 inline from nf)
    k_fused<true><<<GRID, 512, 0, stream>>>(A1p, W1T, H0, node_feat, W_np, b_np, H0);
    // iter 2: gather(H0) -> A2.hsum; fused reads A2+H0, writes H1
    k_gather<<<NN/4, 256, 0, stream>>>(A2, offs, csr2, H0);
    k_fused<false><<<GRID, 512, 0, stream>>>(A2, W2T, H0, node_feat, W_np, b_np, H1);
    // iter 3: gather(H1); fused reads A2+H1, writes H0
    k_gather<<<NN/4, 256, 0, stream>>>(A2, offs, csr2, H1);
    k_fused<false><<<GRID, 512, 0, stream>>>(A2, W2T, H1, node_feat, W_np, b_np, H0);

    k_sum1<<<NSB, 256, 0, stream>>>(H0, partial);
    k_sum2<<<HD, 256, 0, stream>>>(partial, gsum);
    k_small<<<1, 512, 0, stream>>>(edge_feat, paths, path_mask, path_features,
                                   mod_masks, spec_masks, path_spectrum,
                                   W_ep, b_ep, W_path, b_path, W_mod, b_mod,
                                   c1w, c1b, c2w, c2b, W_val, b_val,
                                   gsum, (float*)d_out);
}

// Round 16
// 283.205 us; speedup vs baseline: 1.1331x; 1.1331x over previous
//
#include <hip/hip_runtime.h>
#include <hip/hip_bf16.h>
#include <math.h>

#define NN 50000
#define NE 800000
#define HD 128
#define FD 16
#define NPATH 16
#define PL 8
#define NM 6
#define NS 320
#define NSB 782   // ceil(NN/64)
#define AK 320    // logical K for iters 2-3 (hsum128 | h128 | ef16 | deg | 1 | pad)
#define A2S 192   // shorts per A2 row (hsum128 | statics64)
#define A2U 96    // uints per A2 row
#define HU 64     // uints per H row
#define AK1 64    // K for iter-1 GEMM (nf16 | nfsum16 | ef16 | deg | 1 | pad)
#define EPB 2048  // edges per histogram/scatter block
#define NBLK 391  // ceil(NE/EPB)
#define NBKT 196  // buckets = dst>>8
#define MBT 391   // ceil(NN/128) m-tiles
#define NEGV -1000000000.0f

typedef unsigned int uint;
typedef unsigned short ushort;
typedef short bf16x8 __attribute__((ext_vector_type(8)));
typedef float f32x4 __attribute__((ext_vector_type(4)));

// fast transcendentals: v_exp_f32 + v_rcp_f32
__device__ __forceinline__ float frcp(float x){ return __builtin_amdgcn_rcpf(x); }
__device__ __forceinline__ float fsigm(float x){ return frcp(1.0f + __expf(-x)); }
__device__ __forceinline__ float ftanh(float x){ return 1.0f - 2.0f*frcp(__expf(2.0f*x) + 1.0f); }

// native bf16 convert
__device__ __forceinline__ ushort f2b(float f){
    union { __hip_bfloat16 h; ushort u; } v;
    v.h = __float2bfloat16(f);
    return v.u;
}
__device__ __forceinline__ float b2f(ushort s){
    union{uint u; float f;} v; v.u = ((uint)s)<<16; return v.f;
}
__device__ __forceinline__ float blo(uint v){ return b2f((ushort)(v&0xFFFF)); }
__device__ __forceinline__ float bhi(uint v){ return b2f((ushort)(v>>16)); }
__device__ __forceinline__ uint pack2(float a, float b){ return (uint)f2b(a) | (((uint)f2b(b))<<16); }

// async global->LDS 16B per lane; LDS dest wave-uniform, global src per-lane
__device__ __forceinline__ void gload16(const void* g, void* l){
    __builtin_amdgcn_global_load_lds(
        (const __attribute__((address_space(1))) unsigned int*)g,
        (__attribute__((address_space(3))) unsigned int*)l,
        16, 0, 0);
}

// ---- counting sort phase 1: per-block bucket histogram ----
__global__ void k_hist(const int* __restrict__ ei, int* __restrict__ C){
    __shared__ int h[NBKT];
    int tid = threadIdx.x, blk = blockIdx.x;
    if (tid < NBKT) h[tid] = 0;
    __syncthreads();
    int e0 = blk*EPB;
    for (int i=tid; i<EPB; i+=256){
        int e = e0+i;
        if (e < NE) atomicAdd(&h[ei[NE+e]>>8], 1);
    }
    __syncthreads();
    if (tid < NBKT) C[blk*NBKT + tid] = h[tid];
}

// ---- phase 2a: per-bucket exclusive prefix over blocks + bucket totals ----
__global__ void k_cscanA(int* __restrict__ C, int* __restrict__ bkttot){
    int b = blockIdx.x*4 + (threadIdx.x>>6);
    int lane = threadIdx.x & 63;
    if (b >= NBKT) return;
    int carry = 0;
    for (int c=0; c<7; ++c){
        int i = c*64 + lane;
        int v = (i<NBLK)? C[i*NBKT + b] : 0;
        int x = v;
        #pragma unroll
        for (int d=1; d<64; d<<=1){ int y = __shfl_up(x,d); if (lane>=d) x += y; }
        if (i<NBLK) C[i*NBKT + b] = carry + (x - v);
        carry += __shfl(x, 63);
    }
    if (lane==0) bkttot[b] = carry;
}

// ---- phase 2b: scan bucket totals -> bucket bases; offs[NN]=NE ----
__global__ void k_bscan(const int* __restrict__ bkttot, int* __restrict__ bktbase,
                        int* __restrict__ offs){
    int tid = threadIdx.x, lane = tid&63, w = tid>>6;
    int v = (tid<NBKT)? bkttot[tid] : 0;
    int x = v;
    #pragma unroll
    for (int d=1; d<64; d<<=1){ int y = __shfl_up(x,d); if (lane>=d) x += y; }
    __shared__ int wsum[4];
    if (lane==63) wsum[w] = x;
    __syncthreads();
    int base = 0;
    #pragma unroll
    for (int j=0;j<4;j++) if (j<w) base += wsum[j];
    int excl = base + x - v;
    if (tid < NBKT) bktbase[tid] = excl;
    if (tid == NBKT){ bktbase[NBKT] = excl; offs[NN] = excl; }
}

// ---- phase 3: scatter edges into bucket-ordered array ----
__global__ void k_scatA(const int* __restrict__ ei, const int* __restrict__ C,
                        const int* __restrict__ bktbase, int2* __restrict__ bkt2){
    __shared__ int cur[NBKT];
    __shared__ int cbase[NBKT];
    int tid = threadIdx.x, blk = blockIdx.x;
    if (tid < NBKT){ cur[tid] = 0; cbase[tid] = bktbase[tid] + C[blk*NBKT + tid]; }
    __syncthreads();
    int e0 = blk*EPB;
    for (int i=tid; i<EPB; i+=256){
        int e = e0+i;
        if (e >= NE) break;
        int dst = ei[NE+e];
        int bkt = dst>>8;
        int r = atomicAdd(&cur[bkt], 1);
        bkt2[cbase[bkt] + r] = make_int2(dst, e);
    }
}

// ---- phase 4: per-bucket per-dst counts + scan -> offs; exact placement ----
__global__ void k_scatB(const int* __restrict__ ei, const int2* __restrict__ bkt2,
                        const int* __restrict__ bktbase,
                        int* __restrict__ offs, int2* __restrict__ csr2){
    __shared__ int cnt[256];
    __shared__ int cur[256];
    __shared__ int wsum[4];
    int b = blockIdx.x, tid = threadIdx.x, lane = tid&63, w = tid>>6;
    int d0 = b<<8;
    cnt[tid] = 0;
    __syncthreads();
    int lo = bktbase[b], hi = bktbase[b+1];
    for (int i=lo+tid; i<hi; i+=256) atomicAdd(&cnt[bkt2[i].x & 255], 1);
    __syncthreads();
    int v = cnt[tid], x = v;
    #pragma unroll
    for (int d=1; d<64; d<<=1){ int y = __shfl_up(x,d); if (lane>=d) x += y; }
    if (lane==63) wsum[w] = x;
    __syncthreads();
    int base = 0;
    #pragma unroll
    for (int j=0;j<4;j++) if (j<w) base += wsum[j];
    int o = lo + base + x - v;
    if (d0+tid < NN) offs[d0+tid] = o;
    cur[tid] = o;
    __syncthreads();
    for (int i=lo+tid; i<hi; i+=256){
        int2 p = bkt2[i];
        int pos = atomicAdd(&cur[p.x & 255], 1);
        csr2[pos] = make_int2(ei[p.y], p.y);
    }
}

// ---- per-node 16-wide sums of edge_feat (by eid) and node_feat (by src) ----
__global__ void k_gat16(const int2* __restrict__ csr2,
                        const float* __restrict__ edge_feat, const float* __restrict__ nf,
                        const int* __restrict__ offs,
                        float* __restrict__ ef_sum, float* __restrict__ nf_sum){
    int node = blockIdx.x*4 + (threadIdx.x>>6);
    int lane = threadIdx.x & 63;
    int k = lane & 15, sub = lane >> 4;
    int b = offs[node], e2 = offs[node+1];
    float ae = 0.f, an = 0.f;
    int i = b + sub;
    for (; i + 4 < e2; i += 8){
        int2 p0 = csr2[i], p1 = csr2[i+4];
        float f0 = edge_feat[(size_t)p0.y*FD + k];
        float g0 = nf[(size_t)p0.x*FD + k];
        float f1 = edge_feat[(size_t)p1.y*FD + k];
        float g1 = nf[(size_t)p1.x*FD + k];
        ae += f0 + f1; an += g0 + g1;
    }
    if (i < e2){
        int2 p0 = csr2[i];
        ae += edge_feat[(size_t)p0.y*FD + k];
        an += nf[(size_t)p0.x*FD + k];
    }
    ae += __shfl_xor(ae, 16); ae += __shfl_xor(ae, 32);
    an += __shfl_xor(an, 16); an += __shfl_xor(an, 32);
    if (sub == 0){ ef_sum[node*FD + k] = ae; nf_sum[node*FD + k] = an; }
}

// ---- Wf = W_ep@W_e ; bfv = b_ep@W_e + b_msg ----
__global__ void k_folds(const float* __restrict__ W_ep, const float* __restrict__ b_ep,
                        const float* __restrict__ W_msg, const float* __restrict__ b_msg,
                        float* __restrict__ Wf, float* __restrict__ bfv){
    int o = blockIdx.x*256 + threadIdx.x;
    if (o < FD*HD){
        int k=o>>7, c=o&127;
        float acc=0.f;
        for (int m=0;m<HD;m++) acc += W_ep[k*HD+m]*W_msg[(HD+m)*HD+c];
        Wf[o]=acc;
    } else if (o < FD*HD+HD){
        int c=o-FD*HD;
        float acc=b_msg[c];
        for (int m=0;m<HD;m++) acc += b_ep[m]*W_msg[(HD+m)*HD+c];
        bfv[c]=acc;
    }
}

// ---- build folded mega-weight W2T[512][320], col-INTERLEAVED gates: col = 4*j + g ----
__global__ void k_wprep2(const float* __restrict__ W_ih, const float* __restrict__ W_hh,
                         const float* __restrict__ W_msg, const float* __restrict__ Wf,
                         const float* __restrict__ bfv,
                         const float* __restrict__ b_ih, const float* __restrict__ b_hh,
                         ushort* __restrict__ W2T, float* __restrict__ Wt32){
    int c = blockIdx.x;       // 0..511
    int k = threadIdx.x;      // 0..319
    int j = c>>2, g = c&3;
    float v = 0.f;
    if (k < 128){
        float acc = 0.f;
        if (g < 3){   // hsum path: (W_h @ W_ih_g^T)
            const float* wm = W_msg + (size_t)k*HD;
            const float* wi = W_ih + (size_t)(g*HD+j)*HD;
            for (int m=0;m<HD;m++) acc += wm[m]*wi[m];
        }
        Wt32[(size_t)c*HD + k] = acc;
        v = acc;
    } else if (k < 256){      // h path: W_hh gates (none for gi_n)
        int kk = k-128;
        if (g==0)      v = W_hh[(size_t)j*HD+kk];
        else if (g==1) v = W_hh[(size_t)(HD+j)*HD+kk];
        else if (g==3) v = W_hh[(size_t)(2*HD+j)*HD+kk];
    } else if (k < 272){      // ef_sum path
        if (g < 3){
            const float* wf = Wf + (size_t)(k-256)*HD;
            const float* wi = W_ih + (size_t)(g*HD+j)*HD;
            float acc=0.f;
            for (int m=0;m<HD;m++) acc += wf[m]*wi[m];
            v = acc;
        }
    } else if (k == 272){     // deg path
        if (g < 3){
            const float* wi = W_ih + (size_t)(g*HD+j)*HD;
            float acc=0.f;
            for (int m=0;m<HD;m++) acc += bfv[m]*wi[m];
            v = acc;
        }
    } else if (k == 273){     // constant-1: biases
        v = (g==0)? b_ih[j]+b_hh[j] : (g==1)? b_ih[HD+j]+b_hh[HD+j]
          : (g==2)? b_ih[2*HD+j] : b_hh[2*HD+j];
    }
    W2T[(size_t)c*AK + k] = f2b(v);
}

// ---- iter-1 weight W1T[512][64] ----
__global__ void k_wprep1(const float* __restrict__ W_np, const float* __restrict__ b_np,
                         const float* __restrict__ W_hh, const float* __restrict__ Wt32,
                         const ushort* __restrict__ W2T, ushort* __restrict__ W1T){
    int c = blockIdx.x;       // 0..511
    int k = threadIdx.x;      // 0..63
    int j = c>>2, g = c&3;
    float v = 0.f;
    if (k < 16){              // nf path: W_np @ W_hh_g^T  (g2 has no h-term)
        if (g != 2){
            int gp = (g==3)? 2 : g;
            const float* wh = W_hh + (size_t)(gp*HD + j)*HD;
            const float* wn = W_np + (size_t)k*HD;
            float acc=0.f;
            for (int m=0;m<HD;m++) acc += wn[m]*wh[m];
            v = acc;
        }
    } else if (k < 32){       // nf_sum path
        const float* wt = Wt32 + (size_t)c*HD;
        const float* wn = W_np + (size_t)(k-16)*HD;
        float acc=0.f;
        for (int m=0;m<HD;m++) acc += wn[m]*wt[m];
        v = acc;
    } else if (k < 48){       // ef_sum path: copy from W2T
        v = b2f(W2T[(size_t)c*AK + 256 + (k-32)]);
    } else if (k == 48){      // deg
        float acc = b2f(W2T[(size_t)c*AK + 272]);
        const float* wt = Wt32 + (size_t)c*HD;
        for (int m=0;m<HD;m++) acc += b_np[m]*wt[m];
        v = acc;
    } else if (k == 49){      // const-1
        float acc = b2f(W2T[(size_t)c*AK + 273]);
        if (g != 2){
            int gp = (g==3)? 2 : g;
            const float* wh = W_hh + (size_t)(gp*HD + j)*HD;
            for (int m=0;m<HD;m++) acc += b_np[m]*wh[m];
        }
        v = acc;
    }
    W1T[(size_t)c*AK1 + k] = f2b(v);
}

// ---- light prep: A1p[NN][64] = [nf|nfsum|ef|deg|1|0]; statics into A2 ----
__global__ void k_prep2(const float* __restrict__ nf, const float* __restrict__ nf_sum,
                        const float* __restrict__ ef_sum, const int* __restrict__ offs,
                        ushort* __restrict__ A1p, ushort* __restrict__ A2){
    int idx = blockIdx.x*256 + threadIdx.x;   // NN*32
    int n = idx>>5, c2 = idx&31;
    int k = c2*2, k1 = k+1;
    float d = (float)(offs[n+1] - offs[n]);
    float v0 = (k<16)? nf[n*FD+k] : (k<32)? nf_sum[n*FD+k-16] : (k<48)? ef_sum[n*FD+k-32]
             : (k==48)? d : 0.f;
    float v1 = (k1<16)? nf[n*FD+k1] : (k1<32)? nf_sum[n*FD+k1-16] : (k1<48)? ef_sum[n*FD+k1-32]
             : (k1==49)? 1.f : 0.f;
    ((uint*)A1p)[(size_t)n*32 + c2] = pack2(v0,v1);
    int s = k;   // static col 0..63 maps to W2T k=256+s
    float s0 = (s<16)? ef_sum[n*FD + s] : (s==16)? d : 0.f;
    float s1 = (s+1<16)? ef_sum[n*FD + s+1] : (s+1==17)? 1.f : 0.f;
    ((uint*)A2)[(size_t)n*A2U + 64 + c2] = pack2(s0,s1);
}

// ---- fused GEMM + GRU epilogue, 256thr/128x128, XCD-co-located (g,m) remap, async staging ----
// flat grid 1568: xcd=bid&7, g=(bid>>3)&3, m = xcd + 8*(bid>>5)
// K sources (iters 2-3): kk0,1 = A2.hsum; kk2,3 = Hp; kk4 = A2.statics. Ping-pong: read Hp, write Hn.
template<bool IT1>
__global__ __launch_bounds__(256, 4) void k_fused(const ushort* __restrict__ Asrc,
                                                  const ushort* __restrict__ Bt,
                                                  const ushort* __restrict__ Hp,
                                                  const float* __restrict__ nf,
                                                  const float* __restrict__ W_np,
                                                  const float* __restrict__ b_np,
                                                  ushort* __restrict__ Hn){
    __shared__ __align__(16) short LDS[128*128];   // exactly 32KB
    short* As = LDS;
    short* Bs = LDS + 128*64;
    const int bid = blockIdx.x;
    const int xcd = bid & 7;
    const int t = bid >> 3;
    const int gb = t & 3;
    const int mt = xcd + ((t >> 2) << 3);
    if (mt >= MBT) return;
    const int tid = threadIdx.x;
    const int lane = tid & 63, w = tid>>6;
    const int wm = w>>1, wn = w&1;
    const int n0 = gb*128, m0 = mt*128;
    const int rl  = lane>>3;                       // row-in-chunk 0..7
    const int sg  = (lane&7) ^ rl;                 // pre-swizzled global slot
    f32x4 acc[4][4] = {};
    const int nsteps = IT1 ? 1 : 5;
    for (int kk=0; kk<nsteps; ++kk){
        __syncthreads();
        #pragma unroll
        for (int i=0;i<4;i++){
            int cc = w*4 + i;                      // chunk 0..15 (8 rows each)
            int rowl = (cc<<3) + rl;
            int ar = m0 + rowl; if (ar >= NN) ar = NN-1;
            const ushort* ap;
            if constexpr (IT1) ap = Asrc + (size_t)ar*AK1 + sg*8;
            else {
                if (kk < 2)      ap = Asrc + (size_t)ar*A2S + kk*64 + sg*8;
                else if (kk < 4) ap = Hp   + (size_t)ar*HD  + (kk-2)*64 + sg*8;
                else             ap = Asrc + (size_t)ar*A2S + 128 + sg*8;
            }
            gload16(ap, As + cc*512);
            const int AKB = IT1 ? AK1 : AK;
            gload16(Bt + (size_t)(n0+rowl)*AKB + kk*64 + sg*8, Bs + cc*512);
        }
        __syncthreads();
        #pragma unroll
        for (int ksel=0; ksel<2; ++ksel){
            bf16x8 af[4], bfr[4];
            #pragma unroll
            for (int t2=0;t2<4;t2++){
                int arow = wm*64 + t2*16 + (lane&15);
                int aslot = (ksel*4 + (lane>>4)) ^ (arow&7);
                af[t2] = *(const bf16x8*)&As[arow*64 + aslot*8];
                int brow = wn*64 + t2*16 + (lane&15);
                int bslot = (ksel*4 + (lane>>4)) ^ (brow&7);
                bfr[t2] = *(const bf16x8*)&Bs[brow*64 + bslot*8];
            }
            #pragma unroll
            for (int mi=0;mi<4;mi++)
                #pragma unroll
                for (int ni=0;ni<4;ni++)
                    acc[mi][ni] = __builtin_amdgcn_mfma_f32_16x16x32_bf16(af[mi], bfr[ni], acc[mi][ni], 0,0,0);
        }
    }
    // dump gate tile to LDS (bf16), XOR swizzle at 8B (gate-quad) granularity
    __syncthreads();
    #pragma unroll
    for (int mi=0;mi<4;mi++){
        #pragma unroll
        for (int ni=0;ni<4;ni++){
            #pragma unroll
            for (int r=0;r<4;r++){
                int row = wm*64 + mi*16 + (lane>>4)*4 + r;
                int col = wn*64 + ni*16 + (lane&15);
                int pc = (col&3) | (((col>>2) ^ (row&7))<<2);
                LDS[row*128 + pc] = (short)f2b(acc[mi][ni][r]);
            }
        }
    }
    __syncthreads();
    // epilogue: jp = tid&15 (j-pair), rg = tid>>4 (8 rows each); fast-math gates
    {
        int jp = tid&15, rg = tid>>4;
        int jg = (n0>>2) + jp*2;                    // global hidden j (first of pair)
        int hoff = gb*16 + jp;                      // uint offset within H row
        #pragma unroll
        for (int rr=0; rr<8; ++rr){
            int row = rg*8 + rr;
            int n = m0 + row;
            if (n >= NN) continue;
            uint2 g0 = *(const uint2*)&LDS[row*128 + (((jp*2)   ^ (row&7))<<2)];
            uint2 g1 = *(const uint2*)&LDS[row*128 + (((jp*2+1) ^ (row&7))<<2)];
            float ha, hb;
            if constexpr (IT1){
                const float* x = nf + (size_t)n*FD;
                float a = b_np[jg], b = b_np[jg+1];
                #pragma unroll
                for (int k=0;k<FD;k++){
                    float xv = x[k];
                    a += xv*W_np[k*HD + jg];
                    b += xv*W_np[k*HD + jg + 1];
                }
                ha = a; hb = b;
            } else {
                uint vh = ((const uint*)Hp)[(size_t)n*HU + hoff];
                ha = blo(vh); hb = bhi(vh);
            }
            float r0 = fsigm(blo(g0.x)), z0 = fsigm(bhi(g0.x));
            float nn0 = ftanh(blo(g0.y) + r0*bhi(g0.y));
            float r1 = fsigm(blo(g1.x)), z1 = fsigm(bhi(g1.x));
            float nn1 = ftanh(blo(g1.y) + r1*bhi(g1.y));
            float h0 = (1.f-z0)*nn0 + z0*ha;
            float h1 = (1.f-z1)*nn1 + z1*hb;
            ((uint*)Hn)[(size_t)n*HU + hoff] = pack2(h0,h1);
        }
    }
}

// ---- hsum[n] = sum over in-edges of H[src] -> A2.hsum ----
__global__ void k_gather(ushort* __restrict__ A2, const int* __restrict__ offs,
                         const int2* __restrict__ csr2, const ushort* __restrict__ H){
    int node = blockIdx.x*4 + (threadIdx.x>>6);
    int c2 = threadIdx.x & 63;
    int b = offs[node], e2 = offs[node+1];
    float a0 = 0.f, a1 = 0.f;
    const uint* hp = (const uint*)H;
    int i = b;
    for (; i + 8 <= e2; i += 8){
        int s0=csr2[i].x,  s1=csr2[i+1].x, s2=csr2[i+2].x, s3=csr2[i+3].x;
        int s4=csr2[i+4].x,s5=csr2[i+5].x, s6=csr2[i+6].x, s7=csr2[i+7].x;
        uint v0=hp[(size_t)s0*HU+c2], v1=hp[(size_t)s1*HU+c2],
             v2=hp[(size_t)s2*HU+c2], v3=hp[(size_t)s3*HU+c2],
             v4=hp[(size_t)s4*HU+c2], v5=hp[(size_t)s5*HU+c2],
             v6=hp[(size_t)s6*HU+c2], v7=hp[(size_t)s7*HU+c2];
        a0 += blo(v0)+blo(v1)+blo(v2)+blo(v3)+blo(v4)+blo(v5)+blo(v6)+blo(v7);
        a1 += bhi(v0)+bhi(v1)+bhi(v2)+bhi(v3)+bhi(v4)+bhi(v5)+bhi(v6)+bhi(v7);
    }
    if (i + 4 <= e2){
        int s0=csr2[i].x,s1=csr2[i+1].x,s2=csr2[i+2].x,s3=csr2[i+3].x;
        uint v0=hp[(size_t)s0*HU+c2], v1=hp[(size_t)s1*HU+c2],
             v2=hp[(size_t)s2*HU+c2], v3=hp[(size_t)s3*HU+c2];
        a0 += blo(v0)+blo(v1)+blo(v2)+blo(v3);
        a1 += bhi(v0)+bhi(v1)+bhi(v2)+bhi(v3);
        i += 4;
    }
    for (; i < e2; ++i){
        uint v = hp[(size_t)csr2[i].x*HU+c2];
        a0 += blo(v); a1 += bhi(v);
    }
    ((uint*)A2)[(size_t)node*A2U + c2] = pack2(a0,a1);
}

// ---- two-stage column sum of final H ----
__global__ void k_sum1(const ushort* __restrict__ H, float* __restrict__ partial){
    int bid = blockIdx.x, tid = threadIdx.x;
    int lane = tid&63, w2 = tid>>6;
    int nb = bid*64;
    float a0=0.f, a1=0.f;
    const uint* hp = (const uint*)H;
    #pragma unroll
    for (int r=w2; r<64; r+=4){
        int n = nb + r;
        if (n < NN){
            uint v = hp[(size_t)n*HU + lane];
            a0 += blo(v); a1 += bhi(v);
        }
    }
    __shared__ float s0[4][64], s1[4][64];
    s0[w2][lane]=a0; s1[w2][lane]=a1;
    __syncthreads();
    if (w2==0){
        a0 = s0[0][lane]+s0[1][lane]+s0[2][lane]+s0[3][lane];
        a1 = s1[0][lane]+s1[1][lane]+s1[2][lane]+s1[3][lane];
        ((float2*)partial)[(size_t)bid*64 + lane] = make_float2(a0,a1);
    }
}
__global__ void k_sum2(const float* __restrict__ partial, float* __restrict__ gsum){
    int c = blockIdx.x;          // 0..127
    int tid = threadIdx.x;       // 256
    int lane = tid&63, w = tid>>6;
    float a = 0.f;
    for (int b=tid; b<NSB; b+=256) a += partial[(size_t)b*128 + c];
    #pragma unroll
    for (int d=1; d<64; d<<=1) a += __shfl_xor(a, d);
    __shared__ float sh[4];
    if (lane==0) sh[w]=a;
    __syncthreads();
    if (tid==0) gsum[c] = sh[0]+sh[1]+sh[2]+sh[3];
}

// ---- tiny agents + value head, LDS-staged z + wave-parallel reductions ----
__global__ void k_small(const float* __restrict__ ef, const int* __restrict__ paths,
                        const int* __restrict__ pmask, const float* __restrict__ pfeat,
                        const int* __restrict__ mmask, const int* __restrict__ smask,
                        const float* __restrict__ pspec,
                        const float* __restrict__ W_ep, const float* __restrict__ b_ep,
                        const float* __restrict__ W_path, const float* __restrict__ b_path,
                        const float* __restrict__ W_mod, const float* __restrict__ b_mod,
                        const float* __restrict__ c1w, const float* __restrict__ c1b,
                        const float* __restrict__ c2w, const float* __restrict__ c2b,
                        const float* __restrict__ W_val, const float* __restrict__ b_val,
                        const float* __restrict__ gsum, float* __restrict__ out){
    __shared__ float Wep_s[FD][HD];   // 8KB
    __shared__ float esum[NPATH][FD]; // 1KB
    __shared__ float z[NPATH][HD];
    __shared__ float lf[NS];
    __shared__ float spec[NS];
    __shared__ float red[8];
    __shared__ float scal[3];
    __shared__ int   sel[3];
    __shared__ float maxsh;
    int tid = threadIdx.x, lane = tid&63, w = tid>>6;

    for (int i=tid; i<FD*HD; i+=512) Wep_s[i>>7][i&127] = W_ep[i];
    if (tid < NPATH*FD){
        int p = tid>>4, k = tid&15;
        float a = 0.f;
        #pragma unroll
        for (int l=0;l<PL;l++){
            int eid = paths[p*PL + l];
            a += ef[(size_t)eid*FD + k];
        }
        esum[p][k] = a*0.125f;
    }
    __syncthreads();
    #pragma unroll
    for (int i=tid; i<NPATH*HD; i+=512){
        int p = i>>7, c = i&127;
        float a = b_ep[c];
        #pragma unroll
        for (int k=0;k<FD;k++) a += esum[p][k]*Wep_s[k][c];
        z[p][c] = a;
    }
    __syncthreads();
    { // logits_p
        int p = tid>>5, sub = tid&31;
        float part = 0.f;
        #pragma unroll
        for (int c=sub;c<HD;c+=32) part += z[p][c]*W_path[c];
        #pragma unroll
        for (int d=16; d>=1; d>>=1) part += __shfl_xor(part, d);
        if (sub==0) lf[p] = (pmask[p]==0)? NEGV : part + b_path[0];
    }
    __syncthreads();
    if (w==0){
        float v = (lane<NPATH)? lf[lane] : -3.0e38f;
        float m = v;
        #pragma unroll
        for (int d=1; d<64; d<<=1) m = fmaxf(m, __shfl_xor(m, d));
        float e = (lane<NPATH)? __expf(v-m) : 0.f;
        #pragma unroll
        for (int d=1; d<64; d<<=1) e += __shfl_xor(e, d);
        int idx = (lane<NPATH && v==m)? lane : (1<<30);
        #pragma unroll
        for (int d=1; d<64; d<<=1) idx = min(idx, __shfl_xor(idx, d));
        if (lane==0){ sel[0]=idx; scal[0] = -logf(e); }
    }
    __syncthreads();
    int pstar = sel[0];
    if (w < NM){
        float part = 0.f;
        #pragma unroll
        for (int c=lane;c<HD;c+=64) part += z[pstar][c]*W_mod[c*NM + w];
        if (lane<3) part += pfeat[pstar*3+lane]*W_mod[(HD+lane)*NM + w];
        #pragma unroll
        for (int d=1; d<64; d<<=1) part += __shfl_xor(part, d);
        if (lane==0) red[w] = (mmask[pstar*NM + w]==0)? NEGV : part + b_mod[w];
    } else if (w == 7){
        float part = gsum[lane]*W_val[lane] + gsum[lane+64]*W_val[lane+64];
        #pragma unroll
        for (int d=1; d<64; d<<=1) part += __shfl_xor(part, d);
        if (lane==0) scal[2] = part/(float)NN + b_val[0];
    }
    __syncthreads();
    if (w==0){
        float v = (lane<NM)? red[lane] : -3.0e38f;
        float m = v;
        #pragma unroll
        for (int d=1; d<64; d<<=1) m = fmaxf(m, __shfl_xor(m, d));
        float e = (lane<NM)? __expf(v-m) : 0.f;
        #pragma unroll
        for (int d=1; d<64; d<<=1) e += __shfl_xor(e, d);
        int idx = (lane<NM && v==m)? lane : (1<<30);
        #pragma unroll
        for (int d=1; d<64; d<<=1) idx = min(idx, __shfl_xor(idx, d));
        if (lane==0){ sel[1]=idx; scal[1] = -logf(e); }
    }
    __syncthreads();
    int mstar = sel[1];
    if (tid < NS) spec[tid] = pspec[pstar*NS + tid];
    __syncthreads();
    float v = -3.0e38f;
    if (tid < NS){
        float acc = c2b[0];
        #pragma unroll
        for (int ch=0; ch<8; ch++){
            float a = c1b[ch];
            #pragma unroll
            for (int k=0;k<5;k++){
                int ss = tid + k - 2;
                if (ss>=0 && ss<NS) a += spec[ss]*c1w[ch*5+k];
            }
            a = fmaxf(a, 0.f);
            acc += a*c2w[ch];
        }
        v = (smask[pstar*NM*NS + mstar*NS + tid]==0) ? NEGV : acc;
    }
    float m = v;
    #pragma unroll
    for (int d=1; d<64; d<<=1) m = fmaxf(m, __shfl_xor(m, d));
    if (lane==0) red[w] = m;
    __syncthreads();
    if (tid==0){
        float mm = red[0];
        #pragma unroll
        for (int i=1;i<8;i++) mm = fmaxf(mm, red[i]);
        maxsh = mm; sel[2] = 1<<30;
    }
    __syncthreads();
    float M2 = maxsh;
    if (tid<NS && v==M2) atomicMin(&sel[2], tid);
    float e = (tid<NS)? __expf(v-M2) : 0.f;
    #pragma unroll
    for (int d=1; d<64; d<<=1) e += __shfl_xor(e, d);
    if (lane==0) red[w] = e;
    __syncthreads();
    if (tid==0){
        float se = 0.f;
        #pragma unroll
        for (int i=0;i<8;i++) se += red[i];
        out[0] = (float)pstar;
        out[1] = (float)sel[2];
        out[2] = (float)mstar;
        out[3] = scal[0] + scal[1] - logf(se);
        out[4] = scal[2];
    }
}

extern "C" void kernel_launch(void* const* d_in, const int* in_sizes, int n_in,
                              void* d_out, int out_size, void* d_ws, size_t ws_size,
                              hipStream_t stream) {
    (void)in_sizes; (void)n_in; (void)out_size; (void)ws_size;
    const float* node_feat     = (const float*)d_in[0];
    const float* edge_feat     = (const float*)d_in[1];
    const int*   edge_index    = (const int*)d_in[2];
    const int*   paths         = (const int*)d_in[3];
    const int*   path_mask     = (const int*)d_in[4];
    const float* path_features = (const float*)d_in[5];
    const int*   mod_masks     = (const int*)d_in[6];
    const int*   spec_masks    = (const int*)d_in[7];
    const float* path_spectrum = (const float*)d_in[8];
    const float* W_np  = (const float*)d_in[9];
    const float* b_np  = (const float*)d_in[10];
    const float* W_ep  = (const float*)d_in[11];
    const float* b_ep  = (const float*)d_in[12];
    const float* W_msg = (const float*)d_in[13];
    const float* b_msg = (const float*)d_in[14];
    const float* W_ih  = (const float*)d_in[15];
    const float* b_ih  = (const float*)d_in[16];
    const float* W_hh  = (const float*)d_in[17];
    const float* b_hh  = (const float*)d_in[18];
    const float* W_path = (const float*)d_in[19];
    const float* b_path = (const float*)d_in[20];
    const float* W_mod  = (const float*)d_in[21];
    const float* b_mod  = (const float*)d_in[22];
    const float* c1w = (const float*)d_in[23];
    const float* c1b = (const float*)d_in[24];
    const float* c2w = (const float*)d_in[25];
    const float* c2b = (const float*)d_in[26];
    const float* W_val = (const float*)d_in[27];
    const float* b_val = (const float*)d_in[28];

    char* ws = (char*)d_ws;
    size_t off = 0;
    auto alloc = [&](size_t bytes)->char*{
        char* p = ws + off;
        off += (bytes + 255) & ~(size_t)255;
        return p;
    };
    int*    offs    = (int*)alloc((size_t)(NN+1)*4);
    int*    Cmat    = (int*)alloc((size_t)NBLK*NBKT*4);
    int*    bkttot  = (int*)alloc((size_t)NBKT*4);
    int*    bktbase = (int*)alloc((size_t)(NBKT+1)*4);
    int2*   bkt2    = (int2*)alloc((size_t)NE*8);
    int2*   csr2    = (int2*)alloc((size_t)NE*8);
    float*  ef_sum  = (float*)alloc((size_t)NN*FD*4);
    float*  nf_sum  = (float*)alloc((size_t)NN*FD*4);
    float*  Wf      = (float*)alloc((size_t)FD*HD*4);
    float*  bfv     = (float*)alloc((size_t)HD*4);
    ushort* W2T     = (ushort*)alloc((size_t)512*AK*2);
    float*  Wt32    = (float*)alloc((size_t)512*HD*4);
    ushort* W1T     = (ushort*)alloc((size_t)512*AK1*2);
    ushort* A2      = (ushort*)alloc((size_t)NN*A2S*2);
    ushort* A1p     = (ushort*)alloc((size_t)NN*AK1*2);
    ushort* H0      = (ushort*)alloc((size_t)NN*HD*2);
    ushort* H1      = (ushort*)alloc((size_t)NN*HD*2);
    float*  partial = (float*)alloc((size_t)NSB*HD*4);
    float*  gsum    = (float*)alloc((size_t)HD*4);

    k_hist<<<NBLK, 256, 0, stream>>>(edge_index, Cmat);
    k_cscanA<<<(NBKT+3)/4, 256, 0, stream>>>(Cmat, bkttot);
    k_bscan<<<1, 256, 0, stream>>>(bkttot, bktbase, offs);
    k_scatA<<<NBLK, 256, 0, stream>>>(edge_index, Cmat, bktbase, bkt2);
    k_scatB<<<NBKT, 256, 0, stream>>>(edge_index, bkt2, bktbase, offs, csr2);
    k_gat16<<<NN/4, 256, 0, stream>>>(csr2, edge_feat, node_feat, offs, ef_sum, nf_sum);
    k_folds<<<9, 256, 0, stream>>>(W_ep, b_ep, W_msg, b_msg, Wf, bfv);
    k_wprep2<<<512, AK, 0, stream>>>(W_ih, W_hh, W_msg, Wf, bfv, b_ih, b_hh, W2T, Wt32);
    k_wprep1<<<512, AK1, 0, stream>>>(W_np, b_np, W_hh, Wt32, W2T, W1T);
    k_prep2<<<NN*32/256, 256, 0, stream>>>(node_feat, nf_sum, ef_sum, offs, A1p, A2);

    const int GRID = 8*4*49;   // 1568 (xcd, gate, m-chunk); 4 slots idle
    // iter 1: A1p (K=64) -> fused GRU -> H0  (h0 inline from nf)
    k_fused<true><<<GRID, 256, 0, stream>>>(A1p, W1T, H0, node_feat, W_np, b_np, H0);
    // iter 2: gather(H0) -> A2.hsum; fused reads A2+H0, writes H1
    k_gather<<<NN/4, 256, 0, stream>>>(A2, offs, csr2, H0);
    k_fused<false><<<GRID, 256, 0, stream>>>(A2, W2T, H0, node_feat, W_np, b_np, H1);
    // iter 3: gather(H1); fused reads A2+H1, writes H0
    k_gather<<<NN/4, 256, 0, stream>>>(A2, offs, csr2, H1);
    k_fused<false><<<GRID, 256, 0, stream>>>(A2, W2T, H1, node_feat, W_np, b_np, H0);

    k_sum1<<<NSB, 256, 0, stream>>>(H0, partial);
    k_sum2<<<HD, 256, 0, stream>>>(partial, gsum);
    k_small<<<1, 512, 0, stream>>>(edge_feat, paths, path_mask, path_features,
                                   mod_masks, spec_masks, path_spectrum,
                                   W_ep, b_ep, W_path, b_path, W_mod, b_mod,
                                   c1w, c1b, c2w, c2b, W_val, b_val,
                                   gsum, (float*)d_out);
}

// Round 17
// 281.480 us; speedup vs baseline: 1.1401x; 1.0061x over previous
//
#include <hip/hip_runtime.h>
#include <hip/hip_bf16.h>
#include <math.h>

#define NN 50000
#define NE 800000
#define HD 128
#define FD 16
#define NPATH 16
#define PL 8
#define NM 6
#define NS 320
#define NSB 782   // ceil(NN/64)
#define AK 320    // logical K for iters 2-3 (hsum128 | h128 | ef16 | deg | 1 | pad)
#define A2S 192   // shorts per A2 row (hsum128 | statics64)
#define A2U 96    // uints per A2 row
#define HU 64     // uints per H row
#define AK1 64    // K for iter-1 GEMM (nf16 | nfsum16 | ef16 | deg | 1 | pad)
#define EPB 2048  // edges per histogram/scatter block
#define NBLK 391  // ceil(NE/EPB)
#define NBKT 196  // buckets = dst>>8
#define MBT 391   // ceil(NN/128) m-tiles
#define NEGV -1000000000.0f

typedef unsigned int uint;
typedef unsigned short ushort;
typedef short bf16x8 __attribute__((ext_vector_type(8)));
typedef float f32x4 __attribute__((ext_vector_type(4)));

// fast transcendentals: v_exp_f32 + v_rcp_f32
__device__ __forceinline__ float frcp(float x){ return __builtin_amdgcn_rcpf(x); }
__device__ __forceinline__ float fsigm(float x){ return frcp(1.0f + __expf(-x)); }
__device__ __forceinline__ float ftanh(float x){ return 1.0f - 2.0f*frcp(__expf(2.0f*x) + 1.0f); }

// native bf16 convert
__device__ __forceinline__ ushort f2b(float f){
    union { __hip_bfloat16 h; ushort u; } v;
    v.h = __float2bfloat16(f);
    return v.u;
}
__device__ __forceinline__ float b2f(ushort s){
    union{uint u; float f;} v; v.u = ((uint)s)<<16; return v.f;
}
__device__ __forceinline__ float blo(uint v){ return b2f((ushort)(v&0xFFFF)); }
__device__ __forceinline__ float bhi(uint v){ return b2f((ushort)(v>>16)); }
__device__ __forceinline__ uint pack2(float a, float b){ return (uint)f2b(a) | (((uint)f2b(b))<<16); }

// async global->LDS 16B per lane; LDS dest wave-uniform, global src per-lane
__device__ __forceinline__ void gload16(const void* g, void* l){
    __builtin_amdgcn_global_load_lds(
        (const __attribute__((address_space(1))) unsigned int*)g,
        (__attribute__((address_space(3))) unsigned int*)l,
        16, 0, 0);
}

// ---- counting sort phase 1: per-block bucket histogram ----
__global__ void k_hist(const int* __restrict__ ei, int* __restrict__ C){
    __shared__ int h[NBKT];
    int tid = threadIdx.x, blk = blockIdx.x;
    if (tid < NBKT) h[tid] = 0;
    __syncthreads();
    int e0 = blk*EPB;
    for (int i=tid; i<EPB; i+=256){
        int e = e0+i;
        if (e < NE) atomicAdd(&h[ei[NE+e]>>8], 1);
    }
    __syncthreads();
    if (tid < NBKT) C[blk*NBKT + tid] = h[tid];
}

// ---- phase 2a: per-bucket exclusive prefix over blocks + bucket totals ----
__global__ void k_cscanA(int* __restrict__ C, int* __restrict__ bkttot){
    int b = blockIdx.x*4 + (threadIdx.x>>6);
    int lane = threadIdx.x & 63;
    if (b >= NBKT) return;
    int carry = 0;
    for (int c=0; c<7; ++c){
        int i = c*64 + lane;
        int v = (i<NBLK)? C[i*NBKT + b] : 0;
        int x = v;
        #pragma unroll
        for (int d=1; d<64; d<<=1){ int y = __shfl_up(x,d); if (lane>=d) x += y; }
        if (i<NBLK) C[i*NBKT + b] = carry + (x - v);
        carry += __shfl(x, 63);
    }
    if (lane==0) bkttot[b] = carry;
}

// ---- phase 2b: scan bucket totals -> bucket bases; offs[NN]=NE ----
__global__ void k_bscan(const int* __restrict__ bkttot, int* __restrict__ bktbase,
                        int* __restrict__ offs){
    int tid = threadIdx.x, lane = tid&63, w = tid>>6;
    int v = (tid<NBKT)? bkttot[tid] : 0;
    int x = v;
    #pragma unroll
    for (int d=1; d<64; d<<=1){ int y = __shfl_up(x,d); if (lane>=d) x += y; }
    __shared__ int wsum[4];
    if (lane==63) wsum[w] = x;
    __syncthreads();
    int base = 0;
    #pragma unroll
    for (int j=0;j<4;j++) if (j<w) base += wsum[j];
    int excl = base + x - v;
    if (tid < NBKT) bktbase[tid] = excl;
    if (tid == NBKT){ bktbase[NBKT] = excl; offs[NN] = excl; }
}

// ---- phase 3: scatter edges into bucket-ordered array ----
__global__ void k_scatA(const int* __restrict__ ei, const int* __restrict__ C,
                        const int* __restrict__ bktbase, int2* __restrict__ bkt2){
    __shared__ int cur[NBKT];
    __shared__ int cbase[NBKT];
    int tid = threadIdx.x, blk = blockIdx.x;
    if (tid < NBKT){ cur[tid] = 0; cbase[tid] = bktbase[tid] + C[blk*NBKT + tid]; }
    __syncthreads();
    int e0 = blk*EPB;
    for (int i=tid; i<EPB; i+=256){
        int e = e0+i;
        if (e >= NE) break;
        int dst = ei[NE+e];
        int bkt = dst>>8;
        int r = atomicAdd(&cur[bkt], 1);
        bkt2[cbase[bkt] + r] = make_int2(dst, e);
    }
}

// ---- phase 4: per-bucket per-dst counts + scan -> offs; exact placement ----
__global__ void k_scatB(const int* __restrict__ ei, const int2* __restrict__ bkt2,
                        const int* __restrict__ bktbase,
                        int* __restrict__ offs, int2* __restrict__ csr2){
    __shared__ int cnt[256];
    __shared__ int cur[256];
    __shared__ int wsum[4];
    int b = blockIdx.x, tid = threadIdx.x, lane = tid&63, w = tid>>6;
    int d0 = b<<8;
    cnt[tid] = 0;
    __syncthreads();
    int lo = bktbase[b], hi = bktbase[b+1];
    for (int i=lo+tid; i<hi; i+=256) atomicAdd(&cnt[bkt2[i].x & 255], 1);
    __syncthreads();
    int v = cnt[tid], x = v;
    #pragma unroll
    for (int d=1; d<64; d<<=1){ int y = __shfl_up(x,d); if (lane>=d) x += y; }
    if (lane==63) wsum[w] = x;
    __syncthreads();
    int base = 0;
    #pragma unroll
    for (int j=0;j<4;j++) if (j<w) base += wsum[j];
    int o = lo + base + x - v;
    if (d0+tid < NN) offs[d0+tid] = o;
    cur[tid] = o;
    __syncthreads();
    for (int i=lo+tid; i<hi; i+=256){
        int2 p = bkt2[i];
        int pos = atomicAdd(&cur[p.x & 255], 1);
        csr2[pos] = make_int2(ei[p.y], p.y);
    }
}

// ---- per-node 16-wide sums of edge_feat (by eid) and node_feat (by src) ----
__global__ void k_gat16(const int2* __restrict__ csr2,
                        const float* __restrict__ edge_feat, const float* __restrict__ nf,
                        const int* __restrict__ offs,
                        float* __restrict__ ef_sum, float* __restrict__ nf_sum){
    int node = blockIdx.x*4 + (threadIdx.x>>6);
    int lane = threadIdx.x & 63;
    int k = lane & 15, sub = lane >> 4;
    int b = offs[node], e2 = offs[node+1];
    float ae = 0.f, an = 0.f;
    int i = b + sub;
    for (; i + 4 < e2; i += 8){
        int2 p0 = csr2[i], p1 = csr2[i+4];
        float f0 = edge_feat[(size_t)p0.y*FD + k];
        float g0 = nf[(size_t)p0.x*FD + k];
        float f1 = edge_feat[(size_t)p1.y*FD + k];
        float g1 = nf[(size_t)p1.x*FD + k];
        ae += f0 + f1; an += g0 + g1;
    }
    if (i < e2){
        int2 p0 = csr2[i];
        ae += edge_feat[(size_t)p0.y*FD + k];
        an += nf[(size_t)p0.x*FD + k];
    }
    ae += __shfl_xor(ae, 16); ae += __shfl_xor(ae, 32);
    an += __shfl_xor(an, 16); an += __shfl_xor(an, 32);
    if (sub == 0){ ef_sum[node*FD + k] = ae; nf_sum[node*FD + k] = an; }
}

// ---- Wf = W_ep@W_e ; bfv = b_ep@W_e + b_msg ----
__global__ void k_folds(const float* __restrict__ W_ep, const float* __restrict__ b_ep,
                        const float* __restrict__ W_msg, const float* __restrict__ b_msg,
                        float* __restrict__ Wf, float* __restrict__ bfv){
    int o = blockIdx.x*256 + threadIdx.x;
    if (o < FD*HD){
        int k=o>>7, c=o&127;
        float acc=0.f;
        for (int m=0;m<HD;m++) acc += W_ep[k*HD+m]*W_msg[(HD+m)*HD+c];
        Wf[o]=acc;
    } else if (o < FD*HD+HD){
        int c=o-FD*HD;
        float acc=b_msg[c];
        for (int m=0;m<HD;m++) acc += b_ep[m]*W_msg[(HD+m)*HD+c];
        bfv[c]=acc;
    }
}

// ---- build folded mega-weight W2T[512][320], col-INTERLEAVED gates: col = 4*j + g ----
__global__ void k_wprep2(const float* __restrict__ W_ih, const float* __restrict__ W_hh,
                         const float* __restrict__ W_msg, const float* __restrict__ Wf,
                         const float* __restrict__ bfv,
                         const float* __restrict__ b_ih, const float* __restrict__ b_hh,
                         ushort* __restrict__ W2T, float* __restrict__ Wt32){
    int c = blockIdx.x;       // 0..511
    int k = threadIdx.x;      // 0..319
    int j = c>>2, g = c&3;
    float v = 0.f;
    if (k < 128){
        float acc = 0.f;
        if (g < 3){   // hsum path: (W_h @ W_ih_g^T)
            const float* wm = W_msg + (size_t)k*HD;
            const float* wi = W_ih + (size_t)(g*HD+j)*HD;
            for (int m=0;m<HD;m++) acc += wm[m]*wi[m];
        }
        Wt32[(size_t)c*HD + k] = acc;
        v = acc;
    } else if (k < 256){      // h path: W_hh gates (none for gi_n)
        int kk = k-128;
        if (g==0)      v = W_hh[(size_t)j*HD+kk];
        else if (g==1) v = W_hh[(size_t)(HD+j)*HD+kk];
        else if (g==3) v = W_hh[(size_t)(2*HD+j)*HD+kk];
    } else if (k < 272){      // ef_sum path
        if (g < 3){
            const float* wf = Wf + (size_t)(k-256)*HD;
            const float* wi = W_ih + (size_t)(g*HD+j)*HD;
            float acc=0.f;
            for (int m=0;m<HD;m++) acc += wf[m]*wi[m];
            v = acc;
        }
    } else if (k == 272){     // deg path
        if (g < 3){
            const float* wi = W_ih + (size_t)(g*HD+j)*HD;
            float acc=0.f;
            for (int m=0;m<HD;m++) acc += bfv[m]*wi[m];
            v = acc;
        }
    } else if (k == 273){     // constant-1: biases
        v = (g==0)? b_ih[j]+b_hh[j] : (g==1)? b_ih[HD+j]+b_hh[HD+j]
          : (g==2)? b_ih[2*HD+j] : b_hh[2*HD+j];
    }
    W2T[(size_t)c*AK + k] = f2b(v);
}

// ---- iter-1 weight W1T[512][64] ----
__global__ void k_wprep1(const float* __restrict__ W_np, const float* __restrict__ b_np,
                         const float* __restrict__ W_hh, const float* __restrict__ Wt32,
                         const ushort* __restrict__ W2T, ushort* __restrict__ W1T){
    int c = blockIdx.x;       // 0..511
    int k = threadIdx.x;      // 0..63
    int j = c>>2, g = c&3;
    float v = 0.f;
    if (k < 16){              // nf path: W_np @ W_hh_g^T  (g2 has no h-term)
        if (g != 2){
            int gp = (g==3)? 2 : g;
            const float* wh = W_hh + (size_t)(gp*HD + j)*HD;
            const float* wn = W_np + (size_t)k*HD;
            float acc=0.f;
            for (int m=0;m<HD;m++) acc += wn[m]*wh[m];
            v = acc;
        }
    } else if (k < 32){       // nf_sum path
        const float* wt = Wt32 + (size_t)c*HD;
        const float* wn = W_np + (size_t)(k-16)*HD;
        float acc=0.f;
        for (int m=0;m<HD;m++) acc += wn[m]*wt[m];
        v = acc;
    } else if (k < 48){       // ef_sum path: copy from W2T
        v = b2f(W2T[(size_t)c*AK + 256 + (k-32)]);
    } else if (k == 48){      // deg
        float acc = b2f(W2T[(size_t)c*AK + 272]);
        const float* wt = Wt32 + (size_t)c*HD;
        for (int m=0;m<HD;m++) acc += b_np[m]*wt[m];
        v = acc;
    } else if (k == 49){      // const-1
        float acc = b2f(W2T[(size_t)c*AK + 273]);
        if (g != 2){
            int gp = (g==3)? 2 : g;
            const float* wh = W_hh + (size_t)(gp*HD + j)*HD;
            for (int m=0;m<HD;m++) acc += b_np[m]*wh[m];
        }
        v = acc;
    }
    W1T[(size_t)c*AK1 + k] = f2b(v);
}

// ---- light prep: A1p[NN][64] = [nf|nfsum|ef|deg|1|0]; statics into A2 ----
__global__ void k_prep2(const float* __restrict__ nf, const float* __restrict__ nf_sum,
                        const float* __restrict__ ef_sum, const int* __restrict__ offs,
                        ushort* __restrict__ A1p, ushort* __restrict__ A2){
    int idx = blockIdx.x*256 + threadIdx.x;   // NN*32
    int n = idx>>5, c2 = idx&31;
    int k = c2*2, k1 = k+1;
    float d = (float)(offs[n+1] - offs[n]);
    float v0 = (k<16)? nf[n*FD+k] : (k<32)? nf_sum[n*FD+k-16] : (k<48)? ef_sum[n*FD+k-32]
             : (k==48)? d : 0.f;
    float v1 = (k1<16)? nf[n*FD+k1] : (k1<32)? nf_sum[n*FD+k1-16] : (k1<48)? ef_sum[n*FD+k1-32]
             : (k1==49)? 1.f : 0.f;
    ((uint*)A1p)[(size_t)n*32 + c2] = pack2(v0,v1);
    int s = k;   // static col 0..63 maps to W2T k=256+s
    float s0 = (s<16)? ef_sum[n*FD + s] : (s==16)? d : 0.f;
    float s1 = (s+1<16)? ef_sum[n*FD + s+1] : (s+1==17)? 1.f : 0.f;
    ((uint*)A2)[(size_t)n*A2U + 64 + c2] = pack2(s0,s1);
}

// ---- fused GEMM + GRU epilogue, 2-phase prefetch double-buffer (T3-lite) ----
// flat grid 1568: xcd=bid&7, g=(bid>>3)&3, m = xcd + 8*(bid>>5)
// LDS 64KB = 2 buffers x (As 16KB | Bs 16KB); stage(kk+1) issued before MFMA(kk).
// K sources (iters 2-3): kk0,1 = A2.hsum; kk2,3 = Hp; kk4 = A2.statics. Ping-pong Hp->Hn.
template<bool IT1>
__global__ __launch_bounds__(256, 2) void k_fused(const ushort* __restrict__ Asrc,
                                                  const ushort* __restrict__ Bt,
                                                  const ushort* __restrict__ Hp,
                                                  const float* __restrict__ nf,
                                                  const float* __restrict__ W_np,
                                                  const float* __restrict__ b_np,
                                                  ushort* __restrict__ Hn){
    __shared__ __align__(16) short LDS[2*16384];   // 64KB: buf b = LDS + b*16384 (As 8192sh | Bs 8192sh)
    const int bid = blockIdx.x;
    const int xcd = bid & 7;
    const int t = bid >> 3;
    const int gb = t & 3;
    const int mt = xcd + ((t >> 2) << 3);
    if (mt >= MBT) return;
    const int tid = threadIdx.x;
    const int lane = tid & 63, w = tid>>6;
    const int wm = w>>1, wn = w&1;
    const int n0 = gb*128, m0 = mt*128;
    const int rl  = lane>>3;                       // row-in-chunk 0..7
    const int sg  = (lane&7) ^ rl;                 // pre-swizzled global slot
    const int nsteps = IT1 ? 1 : 5;

    auto stage = [&](int kk, int b){
        short* As = LDS + b*16384;
        short* Bs = As + 8192;
        #pragma unroll
        for (int i=0;i<4;i++){
            int cc = w*4 + i;                      // chunk 0..15 (8 rows each)
            int rowl = (cc<<3) + rl;
            int ar = m0 + rowl; if (ar >= NN) ar = NN-1;
            const ushort* ap;
            if constexpr (IT1) ap = Asrc + (size_t)ar*AK1 + sg*8;
            else {
                if (kk < 2)      ap = Asrc + (size_t)ar*A2S + kk*64 + sg*8;
                else if (kk < 4) ap = Hp   + (size_t)ar*HD  + (kk-2)*64 + sg*8;
                else             ap = Asrc + (size_t)ar*A2S + 128 + sg*8;
            }
            gload16(ap, As + cc*512);
            const int AKB = IT1 ? AK1 : AK;
            gload16(Bt + (size_t)(n0+rowl)*AKB + kk*64 + sg*8, Bs + cc*512);
        }
    };

    f32x4 acc[4][4] = {};
    stage(0, 0);
    __syncthreads();                               // drain prologue loads
    for (int kk=0; kk<nsteps; ++kk){
        if (kk+1 < nsteps) stage(kk+1, (kk+1)&1);  // prefetch next tile (async, other buffer)
        short* As = LDS + (kk&1)*16384;
        short* Bs = As + 8192;
        #pragma unroll
        for (int ksel=0; ksel<2; ++ksel){
            bf16x8 af[4], bfr[4];
            #pragma unroll
            for (int t2=0;t2<4;t2++){
                int arow = wm*64 + t2*16 + (lane&15);
                int aslot = (ksel*4 + (lane>>4)) ^ (arow&7);
                af[t2] = *(const bf16x8*)&As[arow*64 + aslot*8];
                int brow = wn*64 + t2*16 + (lane&15);
                int bslot = (ksel*4 + (lane>>4)) ^ (brow&7);
                bfr[t2] = *(const bf16x8*)&Bs[brow*64 + bslot*8];
            }
            #pragma unroll
            for (int mi=0;mi<4;mi++)
                #pragma unroll
                for (int ni=0;ni<4;ni++)
                    acc[mi][ni] = __builtin_amdgcn_mfma_f32_16x16x32_bf16(af[mi], bfr[ni], acc[mi][ni], 0,0,0);
        }
        __syncthreads();                           // drains prefetch; next tile ready
    }
    // dump gate tile to LDS buf0 (bf16), XOR swizzle at 8B (gate-quad) granularity
    #pragma unroll
    for (int mi=0;mi<4;mi++){
        #pragma unroll
        for (int ni=0;ni<4;ni++){
            #pragma unroll
            for (int r=0;r<4;r++){
                int row = wm*64 + mi*16 + (lane>>4)*4 + r;
                int col = wn*64 + ni*16 + (lane&15);
                int pc = (col&3) | (((col>>2) ^ (row&7))<<2);
                LDS[row*128 + pc] = (short)f2b(acc[mi][ni][r]);
            }
        }
    }
    __syncthreads();
    // epilogue: jp = tid&15 (j-pair), rg = tid>>4 (8 rows each); fast-math gates
    {
        int jp = tid&15, rg = tid>>4;
        int jg = (n0>>2) + jp*2;                    // global hidden j (first of pair)
        int hoff = gb*16 + jp;                      // uint offset within H row
        #pragma unroll
        for (int rr=0; rr<8; ++rr){
            int row = rg*8 + rr;
            int n = m0 + row;
            if (n >= NN) continue;
            uint2 g0 = *(const uint2*)&LDS[row*128 + (((jp*2)   ^ (row&7))<<2)];
            uint2 g1 = *(const uint2*)&LDS[row*128 + (((jp*2+1) ^ (row&7))<<2)];
            float ha, hb;
            if constexpr (IT1){
                const float* x = nf + (size_t)n*FD;
                float a = b_np[jg], b = b_np[jg+1];
                #pragma unroll
                for (int k=0;k<FD;k++){
                    float xv = x[k];
                    a += xv*W_np[k*HD + jg];
                    b += xv*W_np[k*HD + jg + 1];
                }
                ha = a; hb = b;
            } else {
                uint vh = ((const uint*)Hp)[(size_t)n*HU + hoff];
                ha = blo(vh); hb = bhi(vh);
            }
            float r0 = fsigm(blo(g0.x)), z0 = fsigm(bhi(g0.x));
            float nn0 = ftanh(blo(g0.y) + r0*bhi(g0.y));
            float r1 = fsigm(blo(g1.x)), z1 = fsigm(bhi(g1.x));
            float nn1 = ftanh(blo(g1.y) + r1*bhi(g1.y));
            float h0 = (1.f-z0)*nn0 + z0*ha;
            float h1 = (1.f-z1)*nn1 + z1*hb;
            ((uint*)Hn)[(size_t)n*HU + hoff] = pack2(h0,h1);
        }
    }
}

// ---- hsum[n] = sum over in-edges of H[src] -> A2.hsum ----
__global__ void k_gather(ushort* __restrict__ A2, const int* __restrict__ offs,
                         const int2* __restrict__ csr2, const ushort* __restrict__ H){
    int node = blockIdx.x*4 + (threadIdx.x>>6);
    int c2 = threadIdx.x & 63;
    int b = offs[node], e2 = offs[node+1];
    float a0 = 0.f, a1 = 0.f;
    const uint* hp = (const uint*)H;
    int i = b;
    for (; i + 8 <= e2; i += 8){
        int s0=csr2[i].x,  s1=csr2[i+1].x, s2=csr2[i+2].x, s3=csr2[i+3].x;
        int s4=csr2[i+4].x,s5=csr2[i+5].x, s6=csr2[i+6].x, s7=csr2[i+7].x;
        uint v0=hp[(size_t)s0*HU+c2], v1=hp[(size_t)s1*HU+c2],
             v2=hp[(size_t)s2*HU+c2], v3=hp[(size_t)s3*HU+c2],
             v4=hp[(size_t)s4*HU+c2], v5=hp[(size_t)s5*HU+c2],
             v6=hp[(size_t)s6*HU+c2], v7=hp[(size_t)s7*HU+c2];
        a0 += blo(v0)+blo(v1)+blo(v2)+blo(v3)+blo(v4)+blo(v5)+blo(v6)+blo(v7);
        a1 += bhi(v0)+bhi(v1)+bhi(v2)+bhi(v3)+bhi(v4)+bhi(v5)+bhi(v6)+bhi(v7);
    }
    if (i + 4 <= e2){
        int s0=csr2[i].x,s1=csr2[i+1].x,s2=csr2[i+2].x,s3=csr2[i+3].x;
        uint v0=hp[(size_t)s0*HU+c2], v1=hp[(size_t)s1*HU+c2],
             v2=hp[(size_t)s2*HU+c2], v3=hp[(size_t)s3*HU+c2];
        a0 += blo(v0)+blo(v1)+blo(v2)+blo(v3);
        a1 += bhi(v0)+bhi(v1)+bhi(v2)+bhi(v3);
        i += 4;
    }
    for (; i < e2; ++i){
        uint v = hp[(size_t)csr2[i].x*HU+c2];
        a0 += blo(v); a1 += bhi(v);
    }
    ((uint*)A2)[(size_t)node*A2U + c2] = pack2(a0,a1);
}

// ---- two-stage column sum of final H ----
__global__ void k_sum1(const ushort* __restrict__ H, float* __restrict__ partial){
    int bid = blockIdx.x, tid = threadIdx.x;
    int lane = tid&63, w2 = tid>>6;
    int nb = bid*64;
    float a0=0.f, a1=0.f;
    const uint* hp = (const uint*)H;
    #pragma unroll
    for (int r=w2; r<64; r+=4){
        int n = nb + r;
        if (n < NN){
            uint v = hp[(size_t)n*HU + lane];
            a0 += blo(v); a1 += bhi(v);
        }
    }
    __shared__ float s0[4][64], s1[4][64];
    s0[w2][lane]=a0; s1[w2][lane]=a1;
    __syncthreads();
    if (w2==0){
        a0 = s0[0][lane]+s0[1][lane]+s0[2][lane]+s0[3][lane];
        a1 = s1[0][lane]+s1[1][lane]+s1[2][lane]+s1[3][lane];
        ((float2*)partial)[(size_t)bid*64 + lane] = make_float2(a0,a1);
    }
}
__global__ void k_sum2(const float* __restrict__ partial, float* __restrict__ gsum){
    int c = blockIdx.x;          // 0..127
    int tid = threadIdx.x;       // 256
    int lane = tid&63, w = tid>>6;
    float a = 0.f;
    for (int b=tid; b<NSB; b+=256) a += partial[(size_t)b*128 + c];
    #pragma unroll
    for (int d=1; d<64; d<<=1) a += __shfl_xor(a, d);
    __shared__ float sh[4];
    if (lane==0) sh[w]=a;
    __syncthreads();
    if (tid==0) gsum[c] = sh[0]+sh[1]+sh[2]+sh[3];
}

// ---- tiny agents + value head, LDS-staged z + wave-parallel reductions ----
__global__ void k_small(const float* __restrict__ ef, const int* __restrict__ paths,
                        const int* __restrict__ pmask, const float* __restrict__ pfeat,
                        const int* __restrict__ mmask, const int* __restrict__ smask,
                        const float* __restrict__ pspec,
                        const float* __restrict__ W_ep, const float* __restrict__ b_ep,
                        const float* __restrict__ W_path, const float* __restrict__ b_path,
                        const float* __restrict__ W_mod, const float* __restrict__ b_mod,
                        const float* __restrict__ c1w, const float* __restrict__ c1b,
                        const float* __restrict__ c2w, const float* __restrict__ c2b,
                        const float* __restrict__ W_val, const float* __restrict__ b_val,
                        const float* __restrict__ gsum, float* __restrict__ out){
    __shared__ float Wep_s[FD][HD];   // 8KB
    __shared__ float esum[NPATH][FD]; // 1KB
    __shared__ float z[NPATH][HD];
    __shared__ float lf[NS];
    __shared__ float spec[NS];
    __shared__ float red[8];
    __shared__ float scal[3];
    __shared__ int   sel[3];
    __shared__ float maxsh;
    int tid = threadIdx.x, lane = tid&63, w = tid>>6;

    for (int i=tid; i<FD*HD; i+=512) Wep_s[i>>7][i&127] = W_ep[i];
    if (tid < NPATH*FD){
        int p = tid>>4, k = tid&15;
        float a = 0.f;
        #pragma unroll
        for (int l=0;l<PL;l++){
            int eid = paths[p*PL + l];
            a += ef[(size_t)eid*FD + k];
        }
        esum[p][k] = a*0.125f;
    }
    __syncthreads();
    #pragma unroll
    for (int i=tid; i<NPATH*HD; i+=512){
        int p = i>>7, c = i&127;
        float a = b_ep[c];
        #pragma unroll
        for (int k=0;k<FD;k++) a += esum[p][k]*Wep_s[k][c];
        z[p][c] = a;
    }
    __syncthreads();
    { // logits_p
        int p = tid>>5, sub = tid&31;
        float part = 0.f;
        #pragma unroll
        for (int c=sub;c<HD;c+=32) part += z[p][c]*W_path[c];
        #pragma unroll
        for (int d=16; d>=1; d>>=1) part += __shfl_xor(part, d);
        if (sub==0) lf[p] = (pmask[p]==0)? NEGV : part + b_path[0];
    }
    __syncthreads();
    if (w==0){
        float v = (lane<NPATH)? lf[lane] : -3.0e38f;
        float m = v;
        #pragma unroll
        for (int d=1; d<64; d<<=1) m = fmaxf(m, __shfl_xor(m, d));
        float e = (lane<NPATH)? __expf(v-m) : 0.f;
        #pragma unroll
        for (int d=1; d<64; d<<=1) e += __shfl_xor(e, d);
        int idx = (lane<NPATH && v==m)? lane : (1<<30);
        #pragma unroll
        for (int d=1; d<64; d<<=1) idx = min(idx, __shfl_xor(idx, d));
        if (lane==0){ sel[0]=idx; scal[0] = -logf(e); }
    }
    __syncthreads();
    int pstar = sel[0];
    if (w < NM){
        float part = 0.f;
        #pragma unroll
        for (int c=lane;c<HD;c+=64) part += z[pstar][c]*W_mod[c*NM + w];
        if (lane<3) part += pfeat[pstar*3+lane]*W_mod[(HD+lane)*NM + w];
        #pragma unroll
        for (int d=1; d<64; d<<=1) part += __shfl_xor(part, d);
        if (lane==0) red[w] = (mmask[pstar*NM + w]==0)? NEGV : part + b_mod[w];
    } else if (w == 7){
        float part = gsum[lane]*W_val[lane] + gsum[lane+64]*W_val[lane+64];
        #pragma unroll
        for (int d=1; d<64; d<<=1) part += __shfl_xor(part, d);
        if (lane==0) scal[2] = part/(float)NN + b_val[0];
    }
    __syncthreads();
    if (w==0){
        float v = (lane<NM)? red[lane] : -3.0e38f;
        float m = v;
        #pragma unroll
        for (int d=1; d<64; d<<=1) m = fmaxf(m, __shfl_xor(m, d));
        float e = (lane<NM)? __expf(v-m) : 0.f;
        #pragma unroll
        for (int d=1; d<64; d<<=1) e += __shfl_xor(e, d);
        int idx = (lane<NM && v==m)? lane : (1<<30);
        #pragma unroll
        for (int d=1; d<64; d<<=1) idx = min(idx, __shfl_xor(idx, d));
        if (lane==0){ sel[1]=idx; scal[1] = -logf(e); }
    }
    __syncthreads();
    int mstar = sel[1];
    if (tid < NS) spec[tid] = pspec[pstar*NS + tid];
    __syncthreads();
    float v = -3.0e38f;
    if (tid < NS){
        float acc = c2b[0];
        #pragma unroll
        for (int ch=0; ch<8; ch++){
            float a = c1b[ch];
            #pragma unroll
            for (int k=0;k<5;k++){
                int ss = tid + k - 2;
                if (ss>=0 && ss<NS) a += spec[ss]*c1w[ch*5+k];
            }
            a = fmaxf(a, 0.f);
            acc += a*c2w[ch];
        }
        v = (smask[pstar*NM*NS + mstar*NS + tid]==0) ? NEGV : acc;
    }
    float m = v;
    #pragma unroll
    for (int d=1; d<64; d<<=1) m = fmaxf(m, __shfl_xor(m, d));
    if (lane==0) red[w] = m;
    __syncthreads();
    if (tid==0){
        float mm = red[0];
        #pragma unroll
        for (int i=1;i<8;i++) mm = fmaxf(mm, red[i]);
        maxsh = mm; sel[2] = 1<<30;
    }
    __syncthreads();
    float M2 = maxsh;
    if (tid<NS && v==M2) atomicMin(&sel[2], tid);
    float e = (tid<NS)? __expf(v-M2) : 0.f;
    #pragma unroll
    for (int d=1; d<64; d<<=1) e += __shfl_xor(e, d);
    if (lane==0) red[w] = e;
    __syncthreads();
    if (tid==0){
        float se = 0.f;
        #pragma unroll
        for (int i=0;i<8;i++) se += red[i];
        out[0] = (float)pstar;
        out[1] = (float)sel[2];
        out[2] = (float)mstar;
        out[3] = scal[0] + scal[1] - logf(se);
        out[4] = scal[2];
    }
}

extern "C" void kernel_launch(void* const* d_in, const int* in_sizes, int n_in,
                              void* d_out, int out_size, void* d_ws, size_t ws_size,
                              hipStream_t stream) {
    (void)in_sizes; (void)n_in; (void)out_size; (void)ws_size;
    const float* node_feat     = (const float*)d_in[0];
    const float* edge_feat     = (const float*)d_in[1];
    const int*   edge_index    = (const int*)d_in[2];
    const int*   paths         = (const int*)d_in[3];
    const int*   path_mask     = (const int*)d_in[4];
    const float* path_features = (const float*)d_in[5];
    const int*   mod_masks     = (const int*)d_in[6];
    const int*   spec_masks    = (const int*)d_in[7];
    const float* path_spectrum = (const float*)d_in[8];
    const float* W_np  = (const float*)d_in[9];
    const float* b_np  = (const float*)d_in[10];
    const float* W_ep  = (const float*)d_in[11];
    const float* b_ep  = (const float*)d_in[12];
    const float* W_msg = (const float*)d_in[13];
    const float* b_msg = (const float*)d_in[14];
    const float* W_ih  = (const float*)d_in[15];
    const float* b_ih  = (const float*)d_in[16];
    const float* W_hh  = (const float*)d_in[17];
    const float* b_hh  = (const float*)d_in[18];
    const float* W_path = (const float*)d_in[19];
    const float* b_path = (const float*)d_in[20];
    const float* W_mod  = (const float*)d_in[21];
    const float* b_mod  = (const float*)d_in[22];
    const float* c1w = (const float*)d_in[23];
    const float* c1b = (const float*)d_in[24];
    const float* c2w = (const float*)d_in[25];
    const float* c2b = (const float*)d_in[26];
    const float* W_val = (const float*)d_in[27];
    const float* b_val = (const float*)d_in[28];

    char* ws = (char*)d_ws;
    size_t off = 0;
    auto alloc = [&](size_t bytes)->char*{
        char* p = ws + off;
        off += (bytes + 255) & ~(size_t)255;
        return p;
    };
    int*    offs    = (int*)alloc((size_t)(NN+1)*4);
    int*    Cmat    = (int*)alloc((size_t)NBLK*NBKT*4);
    int*    bkttot  = (int*)alloc((size_t)NBKT*4);
    int*    bktbase = (int*)alloc((size_t)(NBKT+1)*4);
    int2*   bkt2    = (int2*)alloc((size_t)NE*8);
    int2*   csr2    = (int2*)alloc((size_t)NE*8);
    float*  ef_sum  = (float*)alloc((size_t)NN*FD*4);
    float*  nf_sum  = (float*)alloc((size_t)NN*FD*4);
    float*  Wf      = (float*)alloc((size_t)FD*HD*4);
    float*  bfv     = (float*)alloc((size_t)HD*4);
    ushort* W2T     = (ushort*)alloc((size_t)512*AK*2);
    float*  Wt32    = (float*)alloc((size_t)512*HD*4);
    ushort* W1T     = (ushort*)alloc((size_t)512*AK1*2);
    ushort* A2      = (ushort*)alloc((size_t)NN*A2S*2);
    ushort* A1p     = (ushort*)alloc((size_t)NN*AK1*2);
    ushort* H0      = (ushort*)alloc((size_t)NN*HD*2);
    ushort* H1      = (ushort*)alloc((size_t)NN*HD*2);
    float*  partial = (float*)alloc((size_t)NSB*HD*4);
    float*  gsum    = (float*)alloc((size_t)HD*4);

    k_hist<<<NBLK, 256, 0, stream>>>(edge_index, Cmat);
    k_cscanA<<<(NBKT+3)/4, 256, 0, stream>>>(Cmat, bkttot);
    k_bscan<<<1, 256, 0, stream>>>(bkttot, bktbase, offs);
    k_scatA<<<NBLK, 256, 0, stream>>>(edge_index, Cmat, bktbase, bkt2);
    k_scatB<<<NBKT, 256, 0, stream>>>(edge_index, bkt2, bktbase, offs, csr2);
    k_gat16<<<NN/4, 256, 0, stream>>>(csr2, edge_feat, node_feat, offs, ef_sum, nf_sum);
    k_folds<<<9, 256, 0, stream>>>(W_ep, b_ep, W_msg, b_msg, Wf, bfv);
    k_wprep2<<<512, AK, 0, stream>>>(W_ih, W_hh, W_msg, Wf, bfv, b_ih, b_hh, W2T, Wt32);
    k_wprep1<<<512, AK1, 0, stream>>>(W_np, b_np, W_hh, Wt32, W2T, W1T);
    k_prep2<<<NN*32/256, 256, 0, stream>>>(node_feat, nf_sum, ef_sum, offs, A1p, A2);

    const int GRID = 8*4*49;   // 1568 (xcd, gate, m-chunk); 4 slots idle
    // iter 1: A1p (K=64) -> fused GRU -> H0  (h0 inline from nf)
    k_fused<true><<<GRID, 256, 0, stream>>>(A1p, W1T, H0, node_feat, W_np, b_np, H0);
    // iter 2: gather(H0) -> A2.hsum; fused reads A2+H0, writes H1
    k_gather<<<NN/4, 256, 0, stream>>>(A2, offs, csr2, H0);
    k_fused<false><<<GRID, 256, 0, stream>>>(A2, W2T, H0, node_feat, W_np, b_np, H1);
    // iter 3: gather(H1); fused reads A2+H1, writes H0
    k_gather<<<NN/4, 256, 0, stream>>>(A2, offs, csr2, H1);
    k_fused<false><<<GRID, 256, 0, stream>>>(A2, W2T, H1, node_feat, W_np, b_np, H0);

    k_sum1<<<NSB, 256, 0, stream>>>(H0, partial);
    k_sum2<<<HD, 256, 0, stream>>>(partial, gsum);
    k_small<<<1, 512, 0, stream>>>(edge_feat, paths, path_mask, path_features,
                                   mod_masks, spec_masks, path_spectrum,
                                   W_ep, b_ep, W_path, b_path, W_mod, b_mod,
                                   c1w, c1b, c2w, c2b, W_val, b_val,
                                   gsum, (float*)d_out);
}